// Round 13
// baseline (2455.389 us; speedup 1.0000x reference)
//
#include <hip/hip_runtime.h>
#include <math.h>
#include <type_traits>

#define B_   8
#define L_   512
#define MTOK 4096           // B_*L_
#define D_   768
#define NH_  12
#define DH_  64
#define DFF_ 3072
#define NL_  12

typedef unsigned short u16;
typedef __attribute__((ext_vector_type(4))) float f32x4;
typedef __attribute__((ext_vector_type(8))) short i16x8;
typedef __attribute__((ext_vector_type(8))) __bf16 b16x8;

// Pick whichever vector type the gfx950 bf16 MFMA builtin accepts.
template <typename A, typename = void>
struct PickFrag { using type = i16x8; };
template <typename A>
struct PickFrag<A, std::void_t<decltype(__builtin_amdgcn_mfma_f32_16x16x32_bf16(
    std::declval<A>(), std::declval<A>(), std::declval<f32x4>(), 0, 0, 0))>> {
  using type = A;
};
using frag_t = typename PickFrag<b16x8>::type;

#if __has_builtin(__builtin_amdgcn_global_load_lds)
#define HAS_GLDS 1
#else
#define HAS_GLDS 0
#endif

#define LOG2E 1.44269504088896340736f

__device__ inline u16 f2bf(float f) {
    unsigned u = __float_as_uint(f);
    unsigned r = u + 0x7fffu + ((u >> 16) & 1u);
    return (u16)(r >> 16);
}
__device__ inline float bf2f(u16 b) { return __uint_as_float(((unsigned)b) << 16); }

// compiler-fenced raw barrier (no vmcnt drain, unlike __syncthreads)
__device__ inline void bar_raw() {
    asm volatile("" ::: "memory");
    __builtin_amdgcn_s_barrier();
    asm volatile("" ::: "memory");
}

// XOR swizzle for 128B-row LDS tiles (u16 index units, 16B granules)
__device__ inline int swz8(int row, int c8) { return c8 ^ ((row & 7) << 3); }

__device__ inline void glds16(const u16* g, u16* l) {
#if HAS_GLDS
    __builtin_amdgcn_global_load_lds(
        (const __attribute__((address_space(1))) void*)g,
        (__attribute__((address_space(3))) void*)l, 16, 0, 0);
#else
    *reinterpret_cast<uint4*>(l) = *reinterpret_cast<const uint4*>(g);
#endif
}

// ---------------------------------------------------------------------------
// box sinusoid embedding -> bf16 into emb[t*1536 + 768 + d]
__global__ void k_box_sin(u16* __restrict__ emb, const float* __restrict__ box) {
    int idx = blockIdx.x * blockDim.x + threadIdx.x;
    if (idx >= MTOK * D_) return;
    int t = idx / D_, d = idx % D_;
    int c = d / 192, r = d % 192, j = r >> 1;
    float theta = __expf(-(float)j * (9.210340371976184f / 96.0f));
    float ang = box[t * 4 + c] * theta;
    emb[(size_t)t * 1536 + 768 + d] = f2bf((r & 1) ? sinf(ang) : cosf(ang));
}

// fp32 patch -> bf16 into emb[t*1536 + c]
__global__ void k_cast(u16* __restrict__ emb, const float* __restrict__ in, int n4) {
    int i = blockIdx.x * blockDim.x + threadIdx.x;
    if (i >= n4) return;            // n4 = MTOK*768/4
    int t = i / 192, c4 = (i % 192) * 4;
    float4 v = *reinterpret_cast<const float4*>(in + (size_t)t * 768 + c4);
    unsigned lo = (unsigned)f2bf(v.x) | ((unsigned)f2bf(v.y) << 16);
    unsigned hi = (unsigned)f2bf(v.z) | ((unsigned)f2bf(v.w) << 16);
    *reinterpret_cast<uint2*>(emb + (size_t)t * 1536 + c4) = make_uint2(lo, hi);
}

// combined bias
__global__ void k_addb(float* __restrict__ dst, const float* __restrict__ a,
                       const float* __restrict__ b) {
    int i = blockIdx.x * blockDim.x + threadIdx.x;
    if (i < D_) dst[i] = a[i] + b[i];
}

// ---------------------------------------------------------------------------
// generic transpose-convert (small one-offs): src (K,N) fp32
// -> dst[(n*rs+ro)*ld + co + k] bf16; zero rows for n>=N.
__global__ __launch_bounds__(256) void k_convT(u16* __restrict__ dst,
                                               const float* __restrict__ src,
                                               int K, int N, int ld, int rs,
                                               int ro, int co) {
    __shared__ float t[32][33];
    int bn = blockIdx.x * 32;
    int bk = blockIdx.y * 32;
    int tx = threadIdx.x % 32, ty = threadIdx.x / 32;
    #pragma unroll
    for (int i = 0; i < 4; ++i) {
        int k = bk + ty + i * 8;
        int n = bn + tx;
        t[ty + i * 8][tx] = (n < N) ? src[(size_t)k * N + n] : 0.0f;
    }
    __syncthreads();
    #pragma unroll
    for (int i = 0; i < 4; ++i) {
        int n = bn + ty + i * 8;
        int k = bk + tx;
        dst[(size_t)(n * rs + ro) * ld + co + k] = f2bf(t[tx][ty + i * 8]);
    }
}

// ---------------------------------------------------------------------------
// batched transposers, 32n x 128k tiles, dense 128B-span stores.
// grid (N/32, K/128, Z).

// plain: src[z] (K,N) -> dst[z] (N,K)
__global__ __launch_bounds__(256) void k_convT128(u16* __restrict__ dst,
                                                  const float* __restrict__ src,
                                                  int K, int N) {
    __shared__ float ts[32][131];
    const float* s = src + (size_t)blockIdx.z * K * N;
    u16* d = dst + (size_t)blockIdx.z * K * N;
    int bn = blockIdx.x * 32, bk = blockIdx.y * 128;
    int t = threadIdx.x, rn = t & 31, kr = t >> 5;
    #pragma unroll
    for (int p = 0; p < 16; ++p) {
        int k = p * 8 + kr;
        ts[rn][k] = s[(size_t)(bk + k) * N + bn + rn];
    }
    __syncthreads();
    int n = t >> 3, c = (t & 7) * 8;
    u16 ta[8], tb[8];
    #pragma unroll
    for (int j = 0; j < 8; ++j) ta[j] = f2bf(ts[n][c + j]);
    #pragma unroll
    for (int j = 0; j < 8; ++j) tb[j] = f2bf(ts[n][64 + c + j]);
    u16* dp = &d[(size_t)(bn + n) * K + bk];
    *reinterpret_cast<uint4*>(dp + c)      = *reinterpret_cast<uint4*>(ta);
    *reinterpret_cast<uint4*>(dp + 64 + c) = *reinterpret_cast<uint4*>(tb);
}

// QKV: z = ly*3 + which; dst slab [3][768][768] per layer
__global__ __launch_bounds__(256) void k_convT128_qkv(u16* __restrict__ dst,
                                                      const float* __restrict__ s0,
                                                      const float* __restrict__ s1,
                                                      const float* __restrict__ s2) {
    __shared__ float ts[32][131];
    int ly = blockIdx.z / 3, which = blockIdx.z % 3;
    const float* s = (which == 0 ? s0 : (which == 1 ? s1 : s2)) + (size_t)ly * 768 * 768;
    u16* d = dst + ((size_t)ly * 3 + which) * 768 * 768;
    int bn = blockIdx.x * 32, bk = blockIdx.y * 128;
    int t = threadIdx.x, rn = t & 31, kr = t >> 5;
    #pragma unroll
    for (int p = 0; p < 16; ++p) {
        int k = p * 8 + kr;
        ts[rn][k] = s[(size_t)(bk + k) * 768 + bn + rn];
    }
    __syncthreads();
    int n = t >> 3, c = (t & 7) * 8;
    u16 ta[8], tb[8];
    #pragma unroll
    for (int j = 0; j < 8; ++j) ta[j] = f2bf(ts[n][c + j]);
    #pragma unroll
    for (int j = 0; j < 8; ++j) tb[j] = f2bf(ts[n][64 + c + j]);
    u16* dp = &d[(size_t)(bn + n) * 768 + bk];
    *reinterpret_cast<uint4*>(dp + c)      = *reinterpret_cast<uint4*>(ta);
    *reinterpret_cast<uint4*>(dp + 64 + c) = *reinterpret_cast<uint4*>(tb);
}

// gate/hidden 16-col interleave: z = ly*2 + which; col n -> row (n>>4)*32+(n&15)+which*16
__global__ __launch_bounds__(256) void k_convT128_gh(u16* __restrict__ dst,
                                                     const float* __restrict__ g,
                                                     const float* __restrict__ h) {
    __shared__ float ts[32][131];
    int ly = blockIdx.z >> 1, which = blockIdx.z & 1;
    const float* s = (which ? h : g) + (size_t)ly * 768 * 3072;
    u16* d = dst + (size_t)ly * 6144 * 768;
    int bn = blockIdx.x * 32, bk = blockIdx.y * 128;
    int t = threadIdx.x, rn = t & 31, kr = t >> 5;
    #pragma unroll
    for (int p = 0; p < 16; ++p) {
        int k = p * 8 + kr;
        ts[rn][k] = s[(size_t)(bk + k) * 3072 + bn + rn];
    }
    __syncthreads();
    int n = t >> 3, c = (t & 7) * 8;
    int ng = bn + n;
    int row = ((ng >> 4) << 5) + (ng & 15) + which * 16;
    u16 ta[8], tb[8];
    #pragma unroll
    for (int j = 0; j < 8; ++j) ta[j] = f2bf(ts[n][c + j]);
    #pragma unroll
    for (int j = 0; j < 8; ++j) tb[j] = f2bf(ts[n][64 + c + j]);
    u16* dp = &d[(size_t)row * 768 + bk];
    *reinterpret_cast<uint4*>(dp + c)      = *reinterpret_cast<uint4*>(ta);
    *reinterpret_cast<uint4*>(dp + 64 + c) = *reinterpret_cast<uint4*>(tb);
}

// ---------------------------------------------------------------------------
// fused (vectorized): h += sum_s part[s]; hn = bf16(rmsnorm(h, w)).
// one block (192 thr) per token, float4 lanes. S=0: pure rmsnorm (no h write).
template <int S>
__global__ __launch_bounds__(192) void k_fused_rr(float* __restrict__ h,
                                                  const float* __restrict__ part,
                                                  u16* __restrict__ hn,
                                                  const float* __restrict__ w) {
    int t = blockIdx.x;
    int i4 = threadIdx.x;                       // 0..191 float4 within token
    size_t b4 = (size_t)t * 192 + i4;
    float4 v = reinterpret_cast<const float4*>(h)[b4];
    #pragma unroll
    for (int s = 0; s < S; ++s) {
        float4 p = reinterpret_cast<const float4*>(part + (size_t)s * MTOK * D_)[b4];
        v.x += p.x; v.y += p.y; v.z += p.z; v.w += p.w;
    }
    if (S > 0) reinterpret_cast<float4*>(h)[b4] = v;
    float ss = v.x * v.x + v.y * v.y + v.z * v.z + v.w * v.w;
    for (int off = 32; off > 0; off >>= 1) ss += __shfl_down(ss, off);
    __shared__ float red[3];
    int wid = threadIdx.x >> 6, lane = threadIdx.x & 63;
    if (lane == 0) red[wid] = ss;
    __syncthreads();
    float inv = rsqrtf((red[0] + red[1] + red[2]) / (float)D_ + 1e-6f);
    float4 wv = reinterpret_cast<const float4*>(w)[i4];
    unsigned lo = (unsigned)f2bf(v.x * inv * wv.x) | ((unsigned)f2bf(v.y * inv * wv.y) << 16);
    unsigned hi = (unsigned)f2bf(v.z * inv * wv.z) | ((unsigned)f2bf(v.w * inv * wv.w) << 16);
    *reinterpret_cast<uint2*>(hn + (size_t)t * D_ + i4 * 4) = make_uint2(lo, hi);
}

// ---------------------------------------------------------------------------
// one-time RoPE table: tab[(l*32+j)*2] = cos(l*theta_j), +1 = sin
__global__ void k_rope_tab(float* __restrict__ tab) {
    int idx = blockIdx.x * blockDim.x + threadIdx.x;   // 512*32
    if (idx >= L_ * 32) return;
    int l = idx >> 5, j = idx & 31;
    float theta = __expf(-(float)j * (9.210340371976184f / 32.0f));
    float s, c;
    sincosf((float)l * theta, &s, &c);
    tab[idx * 2] = c;
    tab[idx * 2 + 1] = s;
}

// ---------------------------------------------------------------------------
// 256x256-tile bf16 GEMM for the gate/hidden FFN GEMM (silu epilogue).
__global__ __launch_bounds__(512) void k_gemm512_gh(u16* __restrict__ Cp,
                                                    const u16* __restrict__ A,
                                                    const u16* __restrict__ BT,
                                                    int K, int ldC) {
    __shared__ u16 smem[32768];     // As[2][8192] | Bs[2][8192]
    int tid = threadIdx.x;
    int wid = tid >> 6, lane = tid & 63;

    int nx = gridDim.x, ny = gridDim.y;
    int bid = blockIdx.y * nx + blockIdx.x;
    int nwg = nx * ny;
    int cpx = nwg >> 3;
    int swzb = (bid & 7) * cpx + (bid >> 3);
    int by = swzb / nx, bx = swzb % nx;
    int row0 = by * 256, col0 = bx * 256;
    int wr = wid >> 2, wcn = wid & 3;

    int c0 = tid, c1 = tid + 512;
    int r0 = c0 >> 2, r1 = c1 >> 2;
    int gsrc = (((tid & 3) ^ ((tid >> 3) & 3)) << 3);
    const u16* gA0 = A  + (size_t)(row0 + r0) * K + gsrc;
    const u16* gA1 = A  + (size_t)(row0 + r1) * K + gsrc;
    const u16* gB0 = BT + (size_t)(col0 + r0) * K + gsrc;
    const u16* gB1 = BT + (size_t)(col0 + r1) * K + gsrc;

    auto stage = [&](int buf, int kt) {
        u16* Asb = smem + buf * 8192;
        u16* Bsb = smem + 16384 + buf * 8192;
        glds16(gA0 + kt, &Asb[c0 * 8]);
        glds16(gA1 + kt, &Asb[c1 * 8]);
        glds16(gB0 + kt, &Bsb[c0 * 8]);
        glds16(gB1 + kt, &Bsb[c1 * 8]);
    };

    f32x4 acc[8][4] = {};
    int lr = lane & 15, lg = lane >> 4;
    int lk = (((lg ^ ((lr >> 1) & 3))) << 3);

    stage(0, 0);
    int cur = 0;
    for (int kt = 0; kt < K; kt += 32) {
        bool has_next = (kt + 32 < K);
        if (has_next) stage(cur ^ 1, kt + 32);
        if (has_next) asm volatile("s_waitcnt vmcnt(4) lgkmcnt(0)" ::: "memory");
        else          asm volatile("s_waitcnt vmcnt(0) lgkmcnt(0)" ::: "memory");
        __builtin_amdgcn_sched_barrier(0);
        bar_raw();
        const u16* Asb = smem + cur * 8192;
        const u16* Bsb = smem + 16384 + cur * 8192;
        frag_t af[8], bfr[4];
        #pragma unroll
        for (int m = 0; m < 8; ++m)
            af[m] = *reinterpret_cast<const frag_t*>(&Asb[(wr * 128 + m * 16 + lr) * 32 + lk]);
        #pragma unroll
        for (int n = 0; n < 4; ++n)
            bfr[n] = *reinterpret_cast<const frag_t*>(&Bsb[(wcn * 64 + n * 16 + lr) * 32 + lk]);
        #pragma unroll
        for (int m = 0; m < 8; ++m)
            #pragma unroll
            for (int n = 0; n < 4; ++n)
                acc[m][n] = __builtin_amdgcn_mfma_f32_16x16x32_bf16(af[m], bfr[n], acc[m][n], 0, 0, 0);
        bar_raw();
        cur ^= 1;
    }

    int lcol = lane & 15, rb = (lane >> 4) * 4;
    #pragma unroll
    for (int m = 0; m < 8; ++m) {
        #pragma unroll
        for (int np = 0; np < 2; ++np) {
            int ocol = (col0 >> 1) + wcn * 32 + np * 16 + lcol;
            #pragma unroll
            for (int e = 0; e < 4; ++e) {
                int row = row0 + wr * 128 + m * 16 + rb + e;
                float g = acc[m][2 * np][e], hv = acc[m][2 * np + 1][e];
                float s = g / (1.0f + __expf(-g));
                Cp[(size_t)row * ldC + ocol] = f2bf(s * hv);
            }
        }
    }
}

// ---------------------------------------------------------------------------
// bf16 MFMA GEMM (128x128), double-buffered, counted-vmcnt, XCD swizzle, split-K.
// MODE 0: C=acc(+bias) f32   MODE 1: C += acc f32 (direct residual accumulate)
// MODE 3: C=acc bf16         MODE 4: partial fp32 store (split-K)
// MODE 6: fused QKV epilogue (rope Q/K [exp2-domain Q scale] + V transpose)
template <int MODE>
__global__ __launch_bounds__(256) void k_gemm_bf16(void* __restrict__ Cp,
                                                   const u16* __restrict__ A,
                                                   const u16* __restrict__ BT,
                                                   const float* __restrict__ bias,
                                                   int K, int Nout, int ldC) {
    __shared__ u16 smem[16384];          // As[2][4096] | Bs[2][4096]
    int tid = threadIdx.x;
    int wid = tid >> 6, lane = tid & 63;

    int nx = gridDim.x, ny = gridDim.y, nz = gridDim.z;
    int bid = ((blockIdx.z * ny) + blockIdx.y) * nx + blockIdx.x;
    int nwg = nx * ny * nz;
    int cpx = nwg >> 3;
    int swz = (bid & 7) * cpx + (bid >> 3);
    int sk  = swz / (nx * ny);
    int rem = swz % (nx * ny);
    int by = rem / nx, bx = rem % nx;
    int row0 = by * 128, col0 = bx * 128;
    int wr = wid >> 1, wc = wid & 1;

    int Klen = K / nz;
    int kbeg = sk * Klen;

    int c0 = wid * 128 + lane;          // 0..511
    int c1 = c0 + 64;
    int r0 = c0 >> 2, kc0 = (c0 & 3) * 8;
    int r1 = c1 >> 2, kc1 = (c1 & 3) * 8;
    const u16* gA0 = A  + (size_t)(row0 + r0) * K + kbeg + kc0;
    const u16* gA1 = A  + (size_t)(row0 + r1) * K + kbeg + kc1;
    const u16* gB0 = BT + (size_t)(col0 + r0) * K + kbeg + kc0;
    const u16* gB1 = BT + (size_t)(col0 + r1) * K + kbeg + kc1;

    auto stage = [&](int buf, int kt) {
        u16* Asb = smem + buf * 4096;
        u16* Bsb = smem + 8192 + buf * 4096;
        glds16(gA0 + kt, &Asb[c0 * 8]);
        glds16(gA1 + kt, &Asb[c1 * 8]);
        glds16(gB0 + kt, &Bsb[c0 * 8]);
        glds16(gB1 + kt, &Bsb[c1 * 8]);
    };

    f32x4 acc[4][4] = {};
    int lrow = lane & 15, lk = (lane >> 4) * 8;

    stage(0, 0);
    int cur = 0;
    for (int kt = 0; kt < Klen; kt += 32) {
        bool has_next = (kt + 32 < Klen);
        if (has_next) stage(cur ^ 1, kt + 32);
        if (has_next) asm volatile("s_waitcnt vmcnt(4) lgkmcnt(0)" ::: "memory");
        else          asm volatile("s_waitcnt vmcnt(0) lgkmcnt(0)" ::: "memory");
        __builtin_amdgcn_sched_barrier(0);
        bar_raw();
        const u16* Asb = smem + cur * 4096;
        const u16* Bsb = smem + 8192 + cur * 4096;
        frag_t af[4], bfr[4];
        #pragma unroll
        for (int m = 0; m < 4; ++m)
            af[m] = *reinterpret_cast<const frag_t*>(&Asb[(wr * 64 + m * 16 + lrow) * 32 + lk]);
        #pragma unroll
        for (int n = 0; n < 4; ++n)
            bfr[n] = *reinterpret_cast<const frag_t*>(&Bsb[(wc * 64 + n * 16 + lrow) * 32 + lk]);
        #pragma unroll
        for (int m = 0; m < 4; ++m)
            #pragma unroll
            for (int n = 0; n < 4; ++n)
                acc[m][n] = __builtin_amdgcn_mfma_f32_16x16x32_bf16(af[m], bfr[n], acc[m][n], 0, 0, 0);
        bar_raw();
        cur ^= 1;
    }

    int lcol = lane & 15, rb = (lane >> 4) * 4;

    if (MODE == 6) {
        u16* qkvh = (u16*)Cp;
        const float* tab = bias;
        if (col0 >= 1536) {
            int head_base = (col0 - 1536) >> 6;
            int bb = row0 >> 9;
            int l0 = row0 & 511;
            #pragma unroll
            for (int pass = 0; pass < 2; ++pass) {
                if (wc == pass) {
                    #pragma unroll
                    for (int m = 0; m < 4; ++m) {
                        #pragma unroll
                        for (int n = 0; n < 4; ++n) {
                            int dl = n * 16 + lcol;
                            int rl = wr * 64 + m * 16 + rb;
                            u16 tmp[4];
                            #pragma unroll
                            for (int e = 0; e < 4; ++e) tmp[e] = f2bf(acc[m][n][e]);
                            *reinterpret_cast<uint2*>(&smem[dl * 136 + rl]) =
                                *reinterpret_cast<uint2*>(tmp);
                        }
                    }
                }
                __syncthreads();
                int head = head_base + pass;
                size_t vbase = (size_t)2 * MTOK * 768 +
                               ((size_t)(bb * NH_ + head) * 64) * 512;
                #pragma unroll
                for (int it = 0; it < 4; ++it) {
                    int dd = it * 16 + (tid >> 4);
                    int rr = (tid & 15) * 8;
                    uint4 v4 = *reinterpret_cast<const uint4*>(&smem[dd * 136 + rr]);
                    *reinterpret_cast<uint4*>(&qkvh[vbase + (size_t)dd * 512 + l0 + rr]) = v4;
                }
                __syncthreads();
            }
        } else {
            int sec = col0 / 768;               // 0=Q, 1=K (uniform per block)
            // exp2-domain: fold log2(e) into Q so attn uses bare v_exp_f32
            float qscale = (sec == 0) ? 0.125f * LOG2E : 1.0f;
            #pragma unroll
            for (int m = 0; m < 4; ++m) {
                #pragma unroll
                for (int n = 0; n < 4; ++n) {
                    int col = col0 + wc * 64 + n * 16 + lcol;
                    int head = (col % 768) >> 6;
                    int d = col & 63;
                    #pragma unroll
                    for (int e = 0; e < 4; ++e) {
                        int row = row0 + wr * 64 + m * 16 + rb + e;
                        int bb = row >> 9, l = row & 511;
                        float v = acc[m][n][e];
                        float p = __shfl_xor(v, 1);
                        float2 cs = *reinterpret_cast<const float2*>(
                            tab + ((size_t)l * 32 + (d >> 1)) * 2);
                        float r = (d & 1) ? (p * cs.y + v * cs.x)
                                          : (v * cs.x - p * cs.y);
                        r *= qscale;
                        qkvh[(size_t)sec * MTOK * 768 +
                             ((size_t)(bb * NH_ + head) * 512 + l) * 64 + d] = f2bf(r);
                    }
                }
            }
        }
        return;
    }

    float* Cpart = (MODE == 4)
        ? ((float*)Cp + (size_t)sk * (size_t)(ny * 128) * ldC) : (float*)Cp;
    #pragma unroll
    for (int m = 0; m < 4; ++m) {
        #pragma unroll
        for (int n = 0; n < 4; ++n) {
            int col = col0 + wc * 64 + n * 16 + lcol;
            if (col >= Nout) continue;
            #pragma unroll
            for (int e = 0; e < 4; ++e) {
                int row = row0 + wr * 64 + m * 16 + rb + e;
                float v = acc[m][n][e];
                size_t off = (size_t)row * ldC + col;
                if (MODE == 0) {
                    if (bias) v += bias[col];
                    ((float*)Cp)[off] = v;
                } else if (MODE == 1) {
                    ((float*)Cp)[off] += v;
                } else if (MODE == 3) {
                    ((u16*)Cp)[off] = f2bf(v);
                } else if (MODE == 4) {
                    Cpart[off] = v;
                }
            }
        }
    }
}

// ---------------------------------------------------------------------------
// MFMA flash attention (exp2-domain scores; Q pre-scaled by 0.125*log2e).
// grid (96 bh, 8 qb), 256 thr = 4 waves x 16 q-rows.
__global__ __launch_bounds__(256) void k_attn3(u16* __restrict__ o,
                                               const u16* __restrict__ qh,
                                               const u16* __restrict__ kh,
                                               const u16* __restrict__ vT) {
    int bh = blockIdx.x, qb = blockIdx.y;
    int b = bh / NH_, hh = bh % NH_;
    int tid = threadIdx.x, wid = tid >> 6, lane = tid & 63;
    __shared__ u16 Qs[64][72], Ps[64][72];
    __shared__ u16 Ks[64 * 64], Vs[64 * 64];

    #pragma unroll
    for (int i = 0; i < 2; ++i) {
        int idx = tid + i * 256;
        int r = idx >> 3, c8 = (idx & 7) * 8;
        uint4 v4 = *reinterpret_cast<const uint4*>(
            qh + ((size_t)bh * L_ + qb * 64 + r) * 64 + c8);
        *reinterpret_cast<uint4*>(&Qs[r][c8]) = v4;
    }
    __syncthreads();

    int lr = lane & 15, lg = lane >> 4;
    frag_t aq[2];
    #pragma unroll
    for (int kd = 0; kd < 2; ++kd)
        aq[kd] = *reinterpret_cast<const frag_t*>(&Qs[wid * 16 + lr][kd * 32 + lg * 8]);

    int sr0 = tid >> 3, sc8 = (tid & 7) * 8;
    int sr1 = sr0 + 32;

    f32x4 accO[4] = {};
    float M[4], S[4];
    #pragma unroll
    for (int e = 0; e < 4; ++e) { M[e] = -INFINITY; S[e] = 0.f; }

    uint4 kreg0 = *reinterpret_cast<const uint4*>(kh + ((size_t)bh * L_ + sr0) * 64 + sc8);
    uint4 kreg1 = *reinterpret_cast<const uint4*>(kh + ((size_t)bh * L_ + sr1) * 64 + sc8);
    uint4 vreg0 = *reinterpret_cast<const uint4*>(vT + ((size_t)bh * 64 + sr0) * L_ + sc8);
    uint4 vreg1 = *reinterpret_cast<const uint4*>(vT + ((size_t)bh * 64 + sr1) * L_ + sc8);

    for (int kb = 0; kb <= qb; ++kb) {
        __syncthreads();
        *reinterpret_cast<uint4*>(&Ks[sr0 * 64 + swz8(sr0, sc8)]) = kreg0;
        *reinterpret_cast<uint4*>(&Ks[sr1 * 64 + swz8(sr1, sc8)]) = kreg1;
        *reinterpret_cast<uint4*>(&Vs[sr0 * 64 + swz8(sr0, sc8)]) = vreg0;
        *reinterpret_cast<uint4*>(&Vs[sr1 * 64 + swz8(sr1, sc8)]) = vreg1;
        __syncthreads();
        if (kb < qb) {
            int nb = (kb + 1) * 64;
            kreg0 = *reinterpret_cast<const uint4*>(kh + ((size_t)bh * L_ + nb + sr0) * 64 + sc8);
            kreg1 = *reinterpret_cast<const uint4*>(kh + ((size_t)bh * L_ + nb + sr1) * 64 + sc8);
            vreg0 = *reinterpret_cast<const uint4*>(vT + ((size_t)bh * 64 + sr0) * L_ + nb + sc8);
            vreg1 = *reinterpret_cast<const uint4*>(vT + ((size_t)bh * 64 + sr1) * L_ + nb + sc8);
        }

        f32x4 sv[4];
        __builtin_amdgcn_s_setprio(1);
        #pragma unroll
        for (int ct = 0; ct < 4; ++ct) {
            int krow = ct * 16 + lr;
            frag_t bk0 = *reinterpret_cast<const frag_t*>(&Ks[krow * 64 + swz8(krow, lg * 8)]);
            frag_t bk1 = *reinterpret_cast<const frag_t*>(&Ks[krow * 64 + swz8(krow, 32 + lg * 8)]);
            f32x4 z = {0.f, 0.f, 0.f, 0.f};
            z = __builtin_amdgcn_mfma_f32_16x16x32_bf16(aq[0], bk0, z, 0, 0, 0);
            sv[ct] = __builtin_amdgcn_mfma_f32_16x16x32_bf16(aq[1], bk1, z, 0, 0, 0);
        }
        __builtin_amdgcn_s_setprio(0);

        bool diag = (kb == qb);
        float mxv[4];
        #pragma unroll
        for (int e = 0; e < 4; ++e) {
            int qg = qb * 64 + wid * 16 + lg * 4 + e;
            float mx = -1e30f;
            #pragma unroll
            for (int ct = 0; ct < 4; ++ct) {
                float s = sv[ct][e];
                if (diag && (kb * 64 + ct * 16 + lr > qg)) s = -1e30f;
                sv[ct][e] = s;
                mx = fmaxf(mx, s);
            }
            #pragma unroll
            for (int msk = 8; msk; msk >>= 1) mx = fmaxf(mx, __shfl_xor(mx, msk));
            mxv[e] = mx;
        }
        bool grow = (mxv[0] > M[0]) | (mxv[1] > M[1]) |
                    (mxv[2] > M[2]) | (mxv[3] > M[3]);
        if (__any(grow)) {
            // full online-softmax update (exp2 domain)
            #pragma unroll
            for (int e = 0; e < 4; ++e) {
                float newM = fmaxf(M[e], mxv[e]);
                float ps = 0.f;
                #pragma unroll
                for (int ct = 0; ct < 4; ++ct) {
                    float p = exp2f(sv[ct][e] - newM);
                    sv[ct][e] = p;
                    ps += p;
                }
                #pragma unroll
                for (int msk = 8; msk; msk >>= 1) ps += __shfl_xor(ps, msk);
                float esc = exp2f(M[e] - newM);
                S[e] = S[e] * esc + ps;
                M[e] = newM;
                #pragma unroll
                for (int dt = 0; dt < 4; ++dt) accO[dt][e] *= esc;
            }
        } else {
            // max unchanged everywhere: esc == 1 exactly, skip rescale
            #pragma unroll
            for (int e = 0; e < 4; ++e) {
                float ps = 0.f;
                #pragma unroll
                for (int ct = 0; ct < 4; ++ct) {
                    float p = exp2f(sv[ct][e] - M[e]);
                    sv[ct][e] = p;
                    ps += p;
                }
                #pragma unroll
                for (int msk = 8; msk; msk >>= 1) ps += __shfl_xor(ps, msk);
                S[e] += ps;
            }
        }

        #pragma unroll
        for (int ct = 0; ct < 4; ++ct)
            #pragma unroll
            for (int e = 0; e < 4; ++e)
                Ps[wid * 16 + lg * 4 + e][ct * 16 + lr] = f2bf(sv[ct][e]);

        frag_t pa0 = *reinterpret_cast<const frag_t*>(&Ps[wid * 16 + lr][lg * 8]);
        frag_t pa1 = *reinterpret_cast<const frag_t*>(&Ps[wid * 16 + lr][32 + lg * 8]);
        __builtin_amdgcn_s_setprio(1);
        #pragma unroll
        for (int dt = 0; dt < 4; ++dt) {
            int vrow = dt * 16 + lr;
            frag_t bv0 = *reinterpret_cast<const frag_t*>(&Vs[vrow * 64 + swz8(vrow, lg * 8)]);
            frag_t bv1 = *reinterpret_cast<const frag_t*>(&Vs[vrow * 64 + swz8(vrow, 32 + lg * 8)]);
            accO[dt] = __builtin_amdgcn_mfma_f32_16x16x32_bf16(pa0, bv0, accO[dt], 0, 0, 0);
            accO[dt] = __builtin_amdgcn_mfma_f32_16x16x32_bf16(pa1, bv1, accO[dt], 0, 0, 0);
        }
        __builtin_amdgcn_s_setprio(0);
    }

    #pragma unroll
    for (int dt = 0; dt < 4; ++dt) {
        #pragma unroll
        for (int e = 0; e < 4; ++e) {
            int row = b * L_ + qb * 64 + wid * 16 + lg * 4 + e;
            o[(size_t)row * D_ + hh * 64 + dt * 16 + lr] = f2bf(accO[dt][e] / S[e]);
        }
    }
}

// ---------------------------------------------------------------------------
// tiny heads: per token, shared rsqrt; reward (2) + box (4) dot products.
__global__ __launch_bounds__(256) void k_heads3(float* __restrict__ out_reward,
                                                float* __restrict__ out_box,
                                                const float* __restrict__ h,
                                                const float* __restrict__ rnw,
                                                const float* __restrict__ rW,
                                                const float* __restrict__ rb,
                                                const float* __restrict__ bnw,
                                                const float* __restrict__ bW,
                                                const float* __restrict__ bb) {
    int t = blockIdx.x;
    size_t base = (size_t)t * D_;
    float x[3];
    float ss = 0.f;
    #pragma unroll
    for (int c = 0; c < 3; ++c) {
        int i = threadIdx.x + c * 256;
        x[c] = h[base + i];
        ss += x[c] * x[c];
    }
    for (int off = 32; off > 0; off >>= 1) ss += __shfl_down(ss, off);
    __shared__ float red[4];
    int wid = threadIdx.x >> 6, lane = threadIdx.x & 63;
    if (lane == 0) red[wid] = ss;
    __syncthreads();
    float inv = rsqrtf((red[0] + red[1] + red[2] + red[3]) / (float)D_ + 1e-6f);

    float a[6] = {};
    #pragma unroll
    for (int c = 0; c < 3; ++c) {
        int i = threadIdx.x + c * 256;
        float xr = x[c] * inv;
        float xw = xr * rnw[i];
        a[0] += xw * rW[i * 2];
        a[1] += xw * rW[i * 2 + 1];
        float xb = xr * bnw[i];
        #pragma unroll
        for (int j = 0; j < 4; ++j) a[2 + j] += xb * bW[i * 4 + j];
    }
    #pragma unroll
    for (int j = 0; j < 6; ++j)
        for (int off = 32; off > 0; off >>= 1) a[j] += __shfl_down(a[j], off);
    __shared__ float red2[4][6];
    if (lane == 0)
        #pragma unroll
        for (int j = 0; j < 6; ++j) red2[wid][j] = a[j];
    __syncthreads();
    if (threadIdx.x < 6) {
        float s = red2[0][threadIdx.x] + red2[1][threadIdx.x] +
                  red2[2][threadIdx.x] + red2[3][threadIdx.x];
        if (threadIdx.x < 2) out_reward[(size_t)t * 2 + threadIdx.x] = s + rb[threadIdx.x];
        else                 out_box[(size_t)t * 4 + threadIdx.x - 2] = s + bb[threadIdx.x - 2];
    }
}

// ---------------------------------------------------------------------------
extern "C" void kernel_launch(void* const* d_in, const int* in_sizes, int n_in,
                              void* d_out, int out_size, void* d_ws, size_t ws_size,
                              hipStream_t stream) {
    const float* patch        = (const float*)d_in[0];
    const float* box          = (const float*)d_in[1];
    const float* patch_W      = (const float*)d_in[2];
    const float* patch_b      = (const float*)d_in[3];
    const float* box_W        = (const float*)d_in[4];
    const float* box_b        = (const float*)d_in[5];
    const float* Wq           = (const float*)d_in[6];
    const float* Wk           = (const float*)d_in[7];
    const float* Wv           = (const float*)d_in[8];
    const float* Wo           = (const float*)d_in[9];
    const float* attn_norm_w  = (const float*)d_in[10];
    const float* gate_W       = (const float*)d_in[11];
    const float* hidden_W     = (const float*)d_in[12];
    const float* ffn_out_W    = (const float*)d_in[13];
    const float* ffn_norm_w   = (const float*)d_in[14];
    const float* reward_norm_w= (const float*)d_in[15];
    const float* reward_W     = (const float*)d_in[16];
    const float* reward_b     = (const float*)d_in[17];
    const float* label_norm_w = (const float*)d_in[18];
    const float* label_W      = (const float*)d_in[19];
    const float* label_b      = (const float*)d_in[20];
    const float* box_norm_w   = (const float*)d_in[21];
    const float* boxh_W       = (const float*)d_in[22];
    const float* boxh_b       = (const float*)d_in[23];

    char* w = (char*)d_ws;
    auto alloc = [&](size_t bytes) { char* p = w; w += (bytes + 255) & ~(size_t)255; return p; };

    u16*  wqkv_a = (u16*)alloc((size_t)NL_ * 2304 * 768 * 2);
    u16*  wo_a   = (u16*)alloc((size_t)NL_ * 768 * 768 * 2);
    u16*  wgh_a  = (u16*)alloc((size_t)NL_ * 6144 * 768 * 2);
    u16*  wfo_a  = (u16*)alloc((size_t)NL_ * 768 * 3072 * 2);
    u16*  wcat   = (u16*)alloc((size_t)768 * 1536 * 2);
    u16*  wlab   = (u16*)alloc((size_t)1024 * 768 * 2);
    float* bias_c= (float*)alloc((size_t)768 * 4);
    u16*  emb    = (u16*)alloc((size_t)MTOK * 1536 * 2);
    float* h     = (float*)alloc((size_t)MTOK * D_ * 4);
    u16*  hn_bf  = (u16*)alloc((size_t)MTOK * D_ * 2);
    u16*  qkvh   = (u16*)alloc((size_t)MTOK * 2304 * 2);  // [q|k|vT] heads layout
    float* tab   = (float*)alloc((size_t)L_ * 32 * 2 * 4);
    u16*  o_bf   = (u16*)alloc((size_t)MTOK * D_ * 2);
    u16*  ga_bf  = (u16*)alloc((size_t)MTOK * DFF_ * 2);
    float* part  = (float*)alloc((size_t)4 * MTOK * D_ * 4);

    u16* qh = qkvh;
    u16* kh = qkvh + (size_t)MTOK * 768;
    u16* vT = qkvh + (size_t)2 * MTOK * 768;

    dim3 blk(256);

    // one-time converts (all layers, batched)
    k_convT<<<dim3(24, 24), blk, 0, stream>>>(wcat, patch_W, 768, 768, 1536, 1, 0, 0);
    k_convT<<<dim3(24, 24), blk, 0, stream>>>(wcat, box_W,   768, 768, 1536, 1, 0, 768);
    k_convT<<<dim3(32, 24), blk, 0, stream>>>(wlab, label_W, 768, 1000, 768, 1, 0, 0);
    k_addb<<<3, blk, 0, stream>>>(bias_c, patch_b, box_b);
    k_rope_tab<<<(L_ * 32 + 255) / 256, blk, 0, stream>>>(tab);
    k_convT128_qkv<<<dim3(24, 6, 36), blk, 0, stream>>>(wqkv_a, Wq, Wk, Wv);
    k_convT128<<<dim3(24, 6, 12), blk, 0, stream>>>(wo_a, Wo, 768, 768);
    k_convT128_gh<<<dim3(96, 6, 24), blk, 0, stream>>>(wgh_a, gate_W, hidden_W);
    k_convT128<<<dim3(24, 24, 12), blk, 0, stream>>>(wfo_a, ffn_out_W, 3072, 768);
    k_cast<<<(MTOK * 768 / 4 + 255) / 256, blk, 0, stream>>>(emb, patch, MTOK * 768 / 4);
    k_box_sin<<<(MTOK * D_ + 255) / 256, blk, 0, stream>>>(emb, box);

    // embedding: h = [patch|box_sin] @ [patch_W; box_W] + (patch_b+box_b)
    k_gemm_bf16<0><<<dim3(6, 32), blk, 0, stream>>>(h, emb, wcat, bias_c, 1536, 768, 768);
    k_fused_rr<0><<<MTOK, dim3(192), 0, stream>>>(h, nullptr, hn_bf, attn_norm_w);

    for (int ly = 0; ly < NL_; ++ly) {
        const u16* wqkv = wqkv_a + (size_t)ly * 2304 * 768;
        const u16* wo_l = wo_a   + (size_t)ly * 768 * 768;
        const u16* wgh  = wgh_a  + (size_t)ly * 6144 * 768;
        const u16* wfo  = wfo_a  + (size_t)ly * 768 * 3072;
        const float* fnw = ffn_norm_w + (size_t)ly * D_;
        const float* nxt = (ly + 1 < NL_) ? attn_norm_w + (size_t)(ly + 1) * D_
                                          : label_norm_w;

        // QKV GEMM with fused rope (exp2-domain Q) + head relayout + V transpose
        k_gemm_bf16<6><<<dim3(18, 32), blk, 0, stream>>>(qkvh, hn_bf, wqkv, tab, 768, 2304, 2304);
        k_attn3<<<dim3(96, 8), blk, 0, stream>>>(o_bf, qh, kh, vT);
        // WO: accumulate directly into h (no split-K partials)
        k_gemm_bf16<1><<<dim3(6, 32), blk, 0, stream>>>(h, o_bf, wo_l, nullptr, 768, 768, 768);
        k_fused_rr<0><<<MTOK, dim3(192), 0, stream>>>(h, nullptr, hn_bf, fnw);

        // GH GEMM: 256x256-tile 512-thread kernel with fused silu
        k_gemm512_gh<<<dim3(24, 16), dim3(512), 0, stream>>>(ga_bf, hn_bf, wgh, 768, 3072);
        // WFO: split-K=2 (half the partial traffic of 4)
        k_gemm_bf16<4><<<dim3(6, 32, 2), blk, 0, stream>>>(part, ga_bf, wfo, nullptr, 3072, 768, 768);
        k_fused_rr<2><<<MTOK, dim3(192), 0, stream>>>(h, part, hn_bf, nxt);
    }

    // heads: hn_bf already = rmsnorm(h, label_norm_w)
    float* out_reward = (float*)d_out;
    float* out_label  = out_reward + (size_t)MTOK * 2;
    float* out_box    = out_label + (size_t)MTOK * 1000;

    k_gemm_bf16<0><<<dim3(8, 32), blk, 0, stream>>>(out_label, hn_bf, wlab, label_b, 768, 1000, 1000);
    k_heads3<<<MTOK, blk, 0, stream>>>(out_reward, out_box, h,
                                       reward_norm_w, reward_W, reward_b,
                                       box_norm_w, boxh_W, boxh_b);
}

// Round 14
// 2332.618 us; speedup vs baseline: 1.0526x; 1.0526x over previous
//
#include <hip/hip_runtime.h>
#include <math.h>
#include <type_traits>

#define B_   8
#define L_   512
#define MTOK 4096           // B_*L_
#define D_   768
#define NH_  12
#define DH_  64
#define DFF_ 3072
#define NL_  12

typedef unsigned short u16;
typedef __attribute__((ext_vector_type(4))) float f32x4;
typedef __attribute__((ext_vector_type(8))) short i16x8;
typedef __attribute__((ext_vector_type(8))) __bf16 b16x8;

// Pick whichever vector type the gfx950 bf16 MFMA builtin accepts.
template <typename A, typename = void>
struct PickFrag { using type = i16x8; };
template <typename A>
struct PickFrag<A, std::void_t<decltype(__builtin_amdgcn_mfma_f32_16x16x32_bf16(
    std::declval<A>(), std::declval<A>(), std::declval<f32x4>(), 0, 0, 0))>> {
  using type = A;
};
using frag_t = typename PickFrag<b16x8>::type;

#if __has_builtin(__builtin_amdgcn_global_load_lds)
#define HAS_GLDS 1
#else
#define HAS_GLDS 0
#endif

#define LOG2E 1.44269504088896340736f

__device__ inline u16 f2bf(float f) {
    unsigned u = __float_as_uint(f);
    unsigned r = u + 0x7fffu + ((u >> 16) & 1u);
    return (u16)(r >> 16);
}
__device__ inline float bf2f(u16 b) { return __uint_as_float(((unsigned)b) << 16); }

// compiler-fenced raw barrier (no vmcnt drain, unlike __syncthreads)
__device__ inline void bar_raw() {
    asm volatile("" ::: "memory");
    __builtin_amdgcn_s_barrier();
    asm volatile("" ::: "memory");
}

// XOR swizzle for 128B-row LDS tiles (u16 index units, 16B granules)
__device__ inline int swz8(int row, int c8) { return c8 ^ ((row & 7) << 3); }

__device__ inline void glds16(const u16* g, u16* l) {
#if HAS_GLDS
    __builtin_amdgcn_global_load_lds(
        (const __attribute__((address_space(1))) void*)g,
        (__attribute__((address_space(3))) void*)l, 16, 0, 0);
#else
    *reinterpret_cast<uint4*>(l) = *reinterpret_cast<const uint4*>(g);
#endif
}

// ---------------------------------------------------------------------------
// box sinusoid embedding -> bf16 into emb[t*1536 + 768 + d]
__global__ void k_box_sin(u16* __restrict__ emb, const float* __restrict__ box) {
    int idx = blockIdx.x * blockDim.x + threadIdx.x;
    if (idx >= MTOK * D_) return;
    int t = idx / D_, d = idx % D_;
    int c = d / 192, r = d % 192, j = r >> 1;
    float theta = __expf(-(float)j * (9.210340371976184f / 96.0f));
    float ang = box[t * 4 + c] * theta;
    emb[(size_t)t * 1536 + 768 + d] = f2bf((r & 1) ? sinf(ang) : cosf(ang));
}

// fp32 patch -> bf16 into emb[t*1536 + c]
__global__ void k_cast(u16* __restrict__ emb, const float* __restrict__ in, int n4) {
    int i = blockIdx.x * blockDim.x + threadIdx.x;
    if (i >= n4) return;            // n4 = MTOK*768/4
    int t = i / 192, c4 = (i % 192) * 4;
    float4 v = *reinterpret_cast<const float4*>(in + (size_t)t * 768 + c4);
    unsigned lo = (unsigned)f2bf(v.x) | ((unsigned)f2bf(v.y) << 16);
    unsigned hi = (unsigned)f2bf(v.z) | ((unsigned)f2bf(v.w) << 16);
    *reinterpret_cast<uint2*>(emb + (size_t)t * 1536 + c4) = make_uint2(lo, hi);
}

// combined bias
__global__ void k_addb(float* __restrict__ dst, const float* __restrict__ a,
                       const float* __restrict__ b) {
    int i = blockIdx.x * blockDim.x + threadIdx.x;
    if (i < D_) dst[i] = a[i] + b[i];
}

// ---------------------------------------------------------------------------
// generic transpose-convert (small one-offs): src (K,N) fp32
// -> dst[(n*rs+ro)*ld + co + k] bf16; zero rows for n>=N.
__global__ __launch_bounds__(256) void k_convT(u16* __restrict__ dst,
                                               const float* __restrict__ src,
                                               int K, int N, int ld, int rs,
                                               int ro, int co) {
    __shared__ float t[32][33];
    int bn = blockIdx.x * 32;
    int bk = blockIdx.y * 32;
    int tx = threadIdx.x % 32, ty = threadIdx.x / 32;
    #pragma unroll
    for (int i = 0; i < 4; ++i) {
        int k = bk + ty + i * 8;
        int n = bn + tx;
        t[ty + i * 8][tx] = (n < N) ? src[(size_t)k * N + n] : 0.0f;
    }
    __syncthreads();
    #pragma unroll
    for (int i = 0; i < 4; ++i) {
        int n = bn + ty + i * 8;
        int k = bk + tx;
        dst[(size_t)(n * rs + ro) * ld + co + k] = f2bf(t[tx][ty + i * 8]);
    }
}

// ---------------------------------------------------------------------------
// batched transposers, 32n x 128k tiles, dense 128B-span stores.
// grid (N/32, K/128, Z).

// plain: src[z] (K,N) -> dst[z] (N,K)
__global__ __launch_bounds__(256) void k_convT128(u16* __restrict__ dst,
                                                  const float* __restrict__ src,
                                                  int K, int N) {
    __shared__ float ts[32][131];
    const float* s = src + (size_t)blockIdx.z * K * N;
    u16* d = dst + (size_t)blockIdx.z * K * N;
    int bn = blockIdx.x * 32, bk = blockIdx.y * 128;
    int t = threadIdx.x, rn = t & 31, kr = t >> 5;
    #pragma unroll
    for (int p = 0; p < 16; ++p) {
        int k = p * 8 + kr;
        ts[rn][k] = s[(size_t)(bk + k) * N + bn + rn];
    }
    __syncthreads();
    int n = t >> 3, c = (t & 7) * 8;
    u16 ta[8], tb[8];
    #pragma unroll
    for (int j = 0; j < 8; ++j) ta[j] = f2bf(ts[n][c + j]);
    #pragma unroll
    for (int j = 0; j < 8; ++j) tb[j] = f2bf(ts[n][64 + c + j]);
    u16* dp = &d[(size_t)(bn + n) * K + bk];
    *reinterpret_cast<uint4*>(dp + c)      = *reinterpret_cast<uint4*>(ta);
    *reinterpret_cast<uint4*>(dp + 64 + c) = *reinterpret_cast<uint4*>(tb);
}

// QKV: z = ly*3 + which; dst slab [3][768][768] per layer
__global__ __launch_bounds__(256) void k_convT128_qkv(u16* __restrict__ dst,
                                                      const float* __restrict__ s0,
                                                      const float* __restrict__ s1,
                                                      const float* __restrict__ s2) {
    __shared__ float ts[32][131];
    int ly = blockIdx.z / 3, which = blockIdx.z % 3;
    const float* s = (which == 0 ? s0 : (which == 1 ? s1 : s2)) + (size_t)ly * 768 * 768;
    u16* d = dst + ((size_t)ly * 3 + which) * 768 * 768;
    int bn = blockIdx.x * 32, bk = blockIdx.y * 128;
    int t = threadIdx.x, rn = t & 31, kr = t >> 5;
    #pragma unroll
    for (int p = 0; p < 16; ++p) {
        int k = p * 8 + kr;
        ts[rn][k] = s[(size_t)(bk + k) * 768 + bn + rn];
    }
    __syncthreads();
    int n = t >> 3, c = (t & 7) * 8;
    u16 ta[8], tb[8];
    #pragma unroll
    for (int j = 0; j < 8; ++j) ta[j] = f2bf(ts[n][c + j]);
    #pragma unroll
    for (int j = 0; j < 8; ++j) tb[j] = f2bf(ts[n][64 + c + j]);
    u16* dp = &d[(size_t)(bn + n) * 768 + bk];
    *reinterpret_cast<uint4*>(dp + c)      = *reinterpret_cast<uint4*>(ta);
    *reinterpret_cast<uint4*>(dp + 64 + c) = *reinterpret_cast<uint4*>(tb);
}

// gate/hidden 16-col interleave: z = ly*2 + which; col n -> row (n>>4)*32+(n&15)+which*16
__global__ __launch_bounds__(256) void k_convT128_gh(u16* __restrict__ dst,
                                                     const float* __restrict__ g,
                                                     const float* __restrict__ h) {
    __shared__ float ts[32][131];
    int ly = blockIdx.z >> 1, which = blockIdx.z & 1;
    const float* s = (which ? h : g) + (size_t)ly * 768 * 3072;
    u16* d = dst + (size_t)ly * 6144 * 768;
    int bn = blockIdx.x * 32, bk = blockIdx.y * 128;
    int t = threadIdx.x, rn = t & 31, kr = t >> 5;
    #pragma unroll
    for (int p = 0; p < 16; ++p) {
        int k = p * 8 + kr;
        ts[rn][k] = s[(size_t)(bk + k) * 3072 + bn + rn];
    }
    __syncthreads();
    int n = t >> 3, c = (t & 7) * 8;
    int ng = bn + n;
    int row = ((ng >> 4) << 5) + (ng & 15) + which * 16;
    u16 ta[8], tb[8];
    #pragma unroll
    for (int j = 0; j < 8; ++j) ta[j] = f2bf(ts[n][c + j]);
    #pragma unroll
    for (int j = 0; j < 8; ++j) tb[j] = f2bf(ts[n][64 + c + j]);
    u16* dp = &d[(size_t)row * 768 + bk];
    *reinterpret_cast<uint4*>(dp + c)      = *reinterpret_cast<uint4*>(ta);
    *reinterpret_cast<uint4*>(dp + 64 + c) = *reinterpret_cast<uint4*>(tb);
}

// ---------------------------------------------------------------------------
// fused (vectorized): h += sum_s part[s]; hn = bf16(rmsnorm(h, w)).
// one block (192 thr) per token, float4 lanes. S=0: pure rmsnorm (no h write).
template <int S>
__global__ __launch_bounds__(192) void k_fused_rr(float* __restrict__ h,
                                                  const float* __restrict__ part,
                                                  u16* __restrict__ hn,
                                                  const float* __restrict__ w) {
    int t = blockIdx.x;
    int i4 = threadIdx.x;                       // 0..191 float4 within token
    size_t b4 = (size_t)t * 192 + i4;
    float4 v = reinterpret_cast<const float4*>(h)[b4];
    #pragma unroll
    for (int s = 0; s < S; ++s) {
        float4 p = reinterpret_cast<const float4*>(part + (size_t)s * MTOK * D_)[b4];
        v.x += p.x; v.y += p.y; v.z += p.z; v.w += p.w;
    }
    if (S > 0) reinterpret_cast<float4*>(h)[b4] = v;
    float ss = v.x * v.x + v.y * v.y + v.z * v.z + v.w * v.w;
    for (int off = 32; off > 0; off >>= 1) ss += __shfl_down(ss, off);
    __shared__ float red[3];
    int wid = threadIdx.x >> 6, lane = threadIdx.x & 63;
    if (lane == 0) red[wid] = ss;
    __syncthreads();
    float inv = rsqrtf((red[0] + red[1] + red[2]) / (float)D_ + 1e-6f);
    float4 wv = reinterpret_cast<const float4*>(w)[i4];
    unsigned lo = (unsigned)f2bf(v.x * inv * wv.x) | ((unsigned)f2bf(v.y * inv * wv.y) << 16);
    unsigned hi = (unsigned)f2bf(v.z * inv * wv.z) | ((unsigned)f2bf(v.w * inv * wv.w) << 16);
    *reinterpret_cast<uint2*>(hn + (size_t)t * D_ + i4 * 4) = make_uint2(lo, hi);
}

// ---------------------------------------------------------------------------
// one-time RoPE table: tab[(l*32+j)*2] = cos(l*theta_j), +1 = sin
__global__ void k_rope_tab(float* __restrict__ tab) {
    int idx = blockIdx.x * blockDim.x + threadIdx.x;   // 512*32
    if (idx >= L_ * 32) return;
    int l = idx >> 5, j = idx & 31;
    float theta = __expf(-(float)j * (9.210340371976184f / 32.0f));
    float s, c;
    sincosf((float)l * theta, &s, &c);
    tab[idx * 2] = c;
    tab[idx * 2 + 1] = s;
}

// ---------------------------------------------------------------------------
// 256x256-tile bf16 GEMM for the gate/hidden FFN GEMM (silu epilogue).
__global__ __launch_bounds__(512) void k_gemm512_gh(u16* __restrict__ Cp,
                                                    const u16* __restrict__ A,
                                                    const u16* __restrict__ BT,
                                                    int K, int ldC) {
    __shared__ u16 smem[32768];     // As[2][8192] | Bs[2][8192]
    int tid = threadIdx.x;
    int wid = tid >> 6, lane = tid & 63;

    int nx = gridDim.x, ny = gridDim.y;
    int bid = blockIdx.y * nx + blockIdx.x;
    int nwg = nx * ny;
    int cpx = nwg >> 3;
    int swzb = (bid & 7) * cpx + (bid >> 3);
    int by = swzb / nx, bx = swzb % nx;
    int row0 = by * 256, col0 = bx * 256;
    int wr = wid >> 2, wcn = wid & 3;

    int c0 = tid, c1 = tid + 512;
    int r0 = c0 >> 2, r1 = c1 >> 2;
    int gsrc = (((tid & 3) ^ ((tid >> 3) & 3)) << 3);
    const u16* gA0 = A  + (size_t)(row0 + r0) * K + gsrc;
    const u16* gA1 = A  + (size_t)(row0 + r1) * K + gsrc;
    const u16* gB0 = BT + (size_t)(col0 + r0) * K + gsrc;
    const u16* gB1 = BT + (size_t)(col0 + r1) * K + gsrc;

    auto stage = [&](int buf, int kt) {
        u16* Asb = smem + buf * 8192;
        u16* Bsb = smem + 16384 + buf * 8192;
        glds16(gA0 + kt, &Asb[c0 * 8]);
        glds16(gA1 + kt, &Asb[c1 * 8]);
        glds16(gB0 + kt, &Bsb[c0 * 8]);
        glds16(gB1 + kt, &Bsb[c1 * 8]);
    };

    f32x4 acc[8][4] = {};
    int lr = lane & 15, lg = lane >> 4;
    int lk = (((lg ^ ((lr >> 1) & 3))) << 3);

    stage(0, 0);
    int cur = 0;
    for (int kt = 0; kt < K; kt += 32) {
        bool has_next = (kt + 32 < K);
        if (has_next) stage(cur ^ 1, kt + 32);
        if (has_next) asm volatile("s_waitcnt vmcnt(4) lgkmcnt(0)" ::: "memory");
        else          asm volatile("s_waitcnt vmcnt(0) lgkmcnt(0)" ::: "memory");
        __builtin_amdgcn_sched_barrier(0);
        bar_raw();
        const u16* Asb = smem + cur * 8192;
        const u16* Bsb = smem + 16384 + cur * 8192;
        frag_t af[8], bfr[4];
        #pragma unroll
        for (int m = 0; m < 8; ++m)
            af[m] = *reinterpret_cast<const frag_t*>(&Asb[(wr * 128 + m * 16 + lr) * 32 + lk]);
        #pragma unroll
        for (int n = 0; n < 4; ++n)
            bfr[n] = *reinterpret_cast<const frag_t*>(&Bsb[(wcn * 64 + n * 16 + lr) * 32 + lk]);
        #pragma unroll
        for (int m = 0; m < 8; ++m)
            #pragma unroll
            for (int n = 0; n < 4; ++n)
                acc[m][n] = __builtin_amdgcn_mfma_f32_16x16x32_bf16(af[m], bfr[n], acc[m][n], 0, 0, 0);
        bar_raw();
        cur ^= 1;
    }

    int lcol = lane & 15, rb = (lane >> 4) * 4;
    #pragma unroll
    for (int m = 0; m < 8; ++m) {
        #pragma unroll
        for (int np = 0; np < 2; ++np) {
            int ocol = (col0 >> 1) + wcn * 32 + np * 16 + lcol;
            #pragma unroll
            for (int e = 0; e < 4; ++e) {
                int row = row0 + wr * 128 + m * 16 + rb + e;
                float g = acc[m][2 * np][e], hv = acc[m][2 * np + 1][e];
                float s = g / (1.0f + __expf(-g));
                Cp[(size_t)row * ldC + ocol] = f2bf(s * hv);
            }
        }
    }
}

// ---------------------------------------------------------------------------
// bf16 MFMA GEMM (128x128), double-buffered, counted-vmcnt, XCD swizzle, split-K.
// MODE 0: C=acc(+bias) f32   MODE 3: C=acc bf16
// MODE 4: partial fp32 store to Cp + sk*M*ldC (split-K)
// MODE 6: fused QKV epilogue (rope Q/K [exp2-domain Q scale] + V transpose)
template <int MODE>
__global__ __launch_bounds__(256) void k_gemm_bf16(void* __restrict__ Cp,
                                                   const u16* __restrict__ A,
                                                   const u16* __restrict__ BT,
                                                   const float* __restrict__ bias,
                                                   int K, int Nout, int ldC) {
    __shared__ u16 smem[16384];          // As[2][4096] | Bs[2][4096]
    int tid = threadIdx.x;
    int wid = tid >> 6, lane = tid & 63;

    int nx = gridDim.x, ny = gridDim.y, nz = gridDim.z;
    int bid = ((blockIdx.z * ny) + blockIdx.y) * nx + blockIdx.x;
    int nwg = nx * ny * nz;
    int cpx = nwg >> 3;
    int swz = (bid & 7) * cpx + (bid >> 3);
    int sk  = swz / (nx * ny);
    int rem = swz % (nx * ny);
    int by = rem / nx, bx = rem % nx;
    int row0 = by * 128, col0 = bx * 128;
    int wr = wid >> 1, wc = wid & 1;

    int Klen = K / nz;
    int kbeg = sk * Klen;

    int c0 = wid * 128 + lane;          // 0..511
    int c1 = c0 + 64;
    int r0 = c0 >> 2, kc0 = (c0 & 3) * 8;
    int r1 = c1 >> 2, kc1 = (c1 & 3) * 8;
    const u16* gA0 = A  + (size_t)(row0 + r0) * K + kbeg + kc0;
    const u16* gA1 = A  + (size_t)(row0 + r1) * K + kbeg + kc1;
    const u16* gB0 = BT + (size_t)(col0 + r0) * K + kbeg + kc0;
    const u16* gB1 = BT + (size_t)(col0 + r1) * K + kbeg + kc1;

    auto stage = [&](int buf, int kt) {
        u16* Asb = smem + buf * 4096;
        u16* Bsb = smem + 8192 + buf * 4096;
        glds16(gA0 + kt, &Asb[c0 * 8]);
        glds16(gA1 + kt, &Asb[c1 * 8]);
        glds16(gB0 + kt, &Bsb[c0 * 8]);
        glds16(gB1 + kt, &Bsb[c1 * 8]);
    };

    f32x4 acc[4][4] = {};
    int lrow = lane & 15, lk = (lane >> 4) * 8;

    stage(0, 0);
    int cur = 0;
    for (int kt = 0; kt < Klen; kt += 32) {
        bool has_next = (kt + 32 < Klen);
        if (has_next) stage(cur ^ 1, kt + 32);
        if (has_next) asm volatile("s_waitcnt vmcnt(4) lgkmcnt(0)" ::: "memory");
        else          asm volatile("s_waitcnt vmcnt(0) lgkmcnt(0)" ::: "memory");
        __builtin_amdgcn_sched_barrier(0);
        bar_raw();
        const u16* Asb = smem + cur * 4096;
        const u16* Bsb = smem + 8192 + cur * 4096;
        frag_t af[4], bfr[4];
        #pragma unroll
        for (int m = 0; m < 4; ++m)
            af[m] = *reinterpret_cast<const frag_t*>(&Asb[(wr * 64 + m * 16 + lrow) * 32 + lk]);
        #pragma unroll
        for (int n = 0; n < 4; ++n)
            bfr[n] = *reinterpret_cast<const frag_t*>(&Bsb[(wc * 64 + n * 16 + lrow) * 32 + lk]);
        #pragma unroll
        for (int m = 0; m < 4; ++m)
            #pragma unroll
            for (int n = 0; n < 4; ++n)
                acc[m][n] = __builtin_amdgcn_mfma_f32_16x16x32_bf16(af[m], bfr[n], acc[m][n], 0, 0, 0);
        bar_raw();
        cur ^= 1;
    }

    int lcol = lane & 15, rb = (lane >> 4) * 4;

    if (MODE == 6) {
        u16* qkvh = (u16*)Cp;
        const float* tab = bias;
        if (col0 >= 1536) {
            int head_base = (col0 - 1536) >> 6;
            int bb = row0 >> 9;
            int l0 = row0 & 511;
            #pragma unroll
            for (int pass = 0; pass < 2; ++pass) {
                if (wc == pass) {
                    #pragma unroll
                    for (int m = 0; m < 4; ++m) {
                        #pragma unroll
                        for (int n = 0; n < 4; ++n) {
                            int dl = n * 16 + lcol;
                            int rl = wr * 64 + m * 16 + rb;
                            u16 tmp[4];
                            #pragma unroll
                            for (int e = 0; e < 4; ++e) tmp[e] = f2bf(acc[m][n][e]);
                            *reinterpret_cast<uint2*>(&smem[dl * 136 + rl]) =
                                *reinterpret_cast<uint2*>(tmp);
                        }
                    }
                }
                __syncthreads();
                int head = head_base + pass;
                size_t vbase = (size_t)2 * MTOK * 768 +
                               ((size_t)(bb * NH_ + head) * 64) * 512;
                #pragma unroll
                for (int it = 0; it < 4; ++it) {
                    int dd = it * 16 + (tid >> 4);
                    int rr = (tid & 15) * 8;
                    uint4 v4 = *reinterpret_cast<const uint4*>(&smem[dd * 136 + rr]);
                    *reinterpret_cast<uint4*>(&qkvh[vbase + (size_t)dd * 512 + l0 + rr]) = v4;
                }
                __syncthreads();
            }
        } else {
            int sec = col0 / 768;               // 0=Q, 1=K (uniform per block)
            // exp2-domain: fold log2(e) into Q so attn uses bare v_exp_f32
            float qscale = (sec == 0) ? 0.125f * LOG2E : 1.0f;
            #pragma unroll
            for (int m = 0; m < 4; ++m) {
                #pragma unroll
                for (int n = 0; n < 4; ++n) {
                    int col = col0 + wc * 64 + n * 16 + lcol;
                    int head = (col % 768) >> 6;
                    int d = col & 63;
                    #pragma unroll
                    for (int e = 0; e < 4; ++e) {
                        int row = row0 + wr * 64 + m * 16 + rb + e;
                        int bb = row >> 9, l = row & 511;
                        float v = acc[m][n][e];
                        float p = __shfl_xor(v, 1);
                        float2 cs = *reinterpret_cast<const float2*>(
                            tab + ((size_t)l * 32 + (d >> 1)) * 2);
                        float r = (d & 1) ? (p * cs.y + v * cs.x)
                                          : (v * cs.x - p * cs.y);
                        r *= qscale;
                        qkvh[(size_t)sec * MTOK * 768 +
                             ((size_t)(bb * NH_ + head) * 512 + l) * 64 + d] = f2bf(r);
                    }
                }
            }
        }
        return;
    }

    float* Cpart = (MODE == 4)
        ? ((float*)Cp + (size_t)sk * (size_t)(ny * 128) * ldC) : (float*)Cp;
    #pragma unroll
    for (int m = 0; m < 4; ++m) {
        #pragma unroll
        for (int n = 0; n < 4; ++n) {
            int col = col0 + wc * 64 + n * 16 + lcol;
            if (col >= Nout) continue;
            #pragma unroll
            for (int e = 0; e < 4; ++e) {
                int row = row0 + wr * 64 + m * 16 + rb + e;
                float v = acc[m][n][e];
                size_t off = (size_t)row * ldC + col;
                if (MODE == 0) {
                    if (bias) v += bias[col];
                    ((float*)Cp)[off] = v;
                } else if (MODE == 3) {
                    ((u16*)Cp)[off] = f2bf(v);
                } else if (MODE == 4) {
                    Cpart[off] = v;
                }
            }
        }
    }
}

// ---------------------------------------------------------------------------
// MFMA flash attention (exp2-domain scores; Q pre-scaled by 0.125*log2e).
// grid (96 bh, 8 qb), 256 thr = 4 waves x 16 q-rows.
__global__ __launch_bounds__(256) void k_attn3(u16* __restrict__ o,
                                               const u16* __restrict__ qh,
                                               const u16* __restrict__ kh,
                                               const u16* __restrict__ vT) {
    int bh = blockIdx.x, qb = blockIdx.y;
    int b = bh / NH_, hh = bh % NH_;
    int tid = threadIdx.x, wid = tid >> 6, lane = tid & 63;
    __shared__ u16 Qs[64][72], Ps[64][72];
    __shared__ u16 Ks[64 * 64], Vs[64 * 64];

    #pragma unroll
    for (int i = 0; i < 2; ++i) {
        int idx = tid + i * 256;
        int r = idx >> 3, c8 = (idx & 7) * 8;
        uint4 v4 = *reinterpret_cast<const uint4*>(
            qh + ((size_t)bh * L_ + qb * 64 + r) * 64 + c8);
        *reinterpret_cast<uint4*>(&Qs[r][c8]) = v4;
    }
    __syncthreads();

    int lr = lane & 15, lg = lane >> 4;
    frag_t aq[2];
    #pragma unroll
    for (int kd = 0; kd < 2; ++kd)
        aq[kd] = *reinterpret_cast<const frag_t*>(&Qs[wid * 16 + lr][kd * 32 + lg * 8]);

    int sr0 = tid >> 3, sc8 = (tid & 7) * 8;
    int sr1 = sr0 + 32;

    f32x4 accO[4] = {};
    float M[4], S[4];
    #pragma unroll
    for (int e = 0; e < 4; ++e) { M[e] = -INFINITY; S[e] = 0.f; }

    uint4 kreg0 = *reinterpret_cast<const uint4*>(kh + ((size_t)bh * L_ + sr0) * 64 + sc8);
    uint4 kreg1 = *reinterpret_cast<const uint4*>(kh + ((size_t)bh * L_ + sr1) * 64 + sc8);
    uint4 vreg0 = *reinterpret_cast<const uint4*>(vT + ((size_t)bh * 64 + sr0) * L_ + sc8);
    uint4 vreg1 = *reinterpret_cast<const uint4*>(vT + ((size_t)bh * 64 + sr1) * L_ + sc8);

    for (int kb = 0; kb <= qb; ++kb) {
        __syncthreads();
        *reinterpret_cast<uint4*>(&Ks[sr0 * 64 + swz8(sr0, sc8)]) = kreg0;
        *reinterpret_cast<uint4*>(&Ks[sr1 * 64 + swz8(sr1, sc8)]) = kreg1;
        *reinterpret_cast<uint4*>(&Vs[sr0 * 64 + swz8(sr0, sc8)]) = vreg0;
        *reinterpret_cast<uint4*>(&Vs[sr1 * 64 + swz8(sr1, sc8)]) = vreg1;
        __syncthreads();
        if (kb < qb) {
            int nb = (kb + 1) * 64;
            kreg0 = *reinterpret_cast<const uint4*>(kh + ((size_t)bh * L_ + nb + sr0) * 64 + sc8);
            kreg1 = *reinterpret_cast<const uint4*>(kh + ((size_t)bh * L_ + nb + sr1) * 64 + sc8);
            vreg0 = *reinterpret_cast<const uint4*>(vT + ((size_t)bh * 64 + sr0) * L_ + nb + sc8);
            vreg1 = *reinterpret_cast<const uint4*>(vT + ((size_t)bh * 64 + sr1) * L_ + nb + sc8);
        }

        f32x4 sv[4];
        __builtin_amdgcn_s_setprio(1);
        #pragma unroll
        for (int ct = 0; ct < 4; ++ct) {
            int krow = ct * 16 + lr;
            frag_t bk0 = *reinterpret_cast<const frag_t*>(&Ks[krow * 64 + swz8(krow, lg * 8)]);
            frag_t bk1 = *reinterpret_cast<const frag_t*>(&Ks[krow * 64 + swz8(krow, 32 + lg * 8)]);
            f32x4 z = {0.f, 0.f, 0.f, 0.f};
            z = __builtin_amdgcn_mfma_f32_16x16x32_bf16(aq[0], bk0, z, 0, 0, 0);
            sv[ct] = __builtin_amdgcn_mfma_f32_16x16x32_bf16(aq[1], bk1, z, 0, 0, 0);
        }
        __builtin_amdgcn_s_setprio(0);

        bool diag = (kb == qb);
        float mxv[4];
        #pragma unroll
        for (int e = 0; e < 4; ++e) {
            int qg = qb * 64 + wid * 16 + lg * 4 + e;
            float mx = -1e30f;
            #pragma unroll
            for (int ct = 0; ct < 4; ++ct) {
                float s = sv[ct][e];
                if (diag && (kb * 64 + ct * 16 + lr > qg)) s = -1e30f;
                sv[ct][e] = s;
                mx = fmaxf(mx, s);
            }
            #pragma unroll
            for (int msk = 8; msk; msk >>= 1) mx = fmaxf(mx, __shfl_xor(mx, msk));
            mxv[e] = mx;
        }
        bool grow = (mxv[0] > M[0]) | (mxv[1] > M[1]) |
                    (mxv[2] > M[2]) | (mxv[3] > M[3]);
        if (__any(grow)) {
            #pragma unroll
            for (int e = 0; e < 4; ++e) {
                float newM = fmaxf(M[e], mxv[e]);
                float ps = 0.f;
                #pragma unroll
                for (int ct = 0; ct < 4; ++ct) {
                    float p = exp2f(sv[ct][e] - newM);
                    sv[ct][e] = p;
                    ps += p;
                }
                #pragma unroll
                for (int msk = 8; msk; msk >>= 1) ps += __shfl_xor(ps, msk);
                float esc = exp2f(M[e] - newM);
                S[e] = S[e] * esc + ps;
                M[e] = newM;
                #pragma unroll
                for (int dt = 0; dt < 4; ++dt) accO[dt][e] *= esc;
            }
        } else {
            #pragma unroll
            for (int e = 0; e < 4; ++e) {
                float ps = 0.f;
                #pragma unroll
                for (int ct = 0; ct < 4; ++ct) {
                    float p = exp2f(sv[ct][e] - M[e]);
                    sv[ct][e] = p;
                    ps += p;
                }
                #pragma unroll
                for (int msk = 8; msk; msk >>= 1) ps += __shfl_xor(ps, msk);
                S[e] += ps;
            }
        }

        #pragma unroll
        for (int ct = 0; ct < 4; ++ct)
            #pragma unroll
            for (int e = 0; e < 4; ++e)
                Ps[wid * 16 + lg * 4 + e][ct * 16 + lr] = f2bf(sv[ct][e]);

        frag_t pa0 = *reinterpret_cast<const frag_t*>(&Ps[wid * 16 + lr][lg * 8]);
        frag_t pa1 = *reinterpret_cast<const frag_t*>(&Ps[wid * 16 + lr][32 + lg * 8]);
        __builtin_amdgcn_s_setprio(1);
        #pragma unroll
        for (int dt = 0; dt < 4; ++dt) {
            int vrow = dt * 16 + lr;
            frag_t bv0 = *reinterpret_cast<const frag_t*>(&Vs[vrow * 64 + swz8(vrow, lg * 8)]);
            frag_t bv1 = *reinterpret_cast<const frag_t*>(&Vs[vrow * 64 + swz8(vrow, 32 + lg * 8)]);
            accO[dt] = __builtin_amdgcn_mfma_f32_16x16x32_bf16(pa0, bv0, accO[dt], 0, 0, 0);
            accO[dt] = __builtin_amdgcn_mfma_f32_16x16x32_bf16(pa1, bv1, accO[dt], 0, 0, 0);
        }
        __builtin_amdgcn_s_setprio(0);
    }

    #pragma unroll
    for (int dt = 0; dt < 4; ++dt) {
        #pragma unroll
        for (int e = 0; e < 4; ++e) {
            int row = b * L_ + qb * 64 + wid * 16 + lg * 4 + e;
            o[(size_t)row * D_ + hh * 64 + dt * 16 + lr] = f2bf(accO[dt][e] / S[e]);
        }
    }
}

// ---------------------------------------------------------------------------
// tiny heads: per token, shared rsqrt; reward (2) + box (4) dot products.
__global__ __launch_bounds__(256) void k_heads3(float* __restrict__ out_reward,
                                                float* __restrict__ out_box,
                                                const float* __restrict__ h,
                                                const float* __restrict__ rnw,
                                                const float* __restrict__ rW,
                                                const float* __restrict__ rb,
                                                const float* __restrict__ bnw,
                                                const float* __restrict__ bW,
                                                const float* __restrict__ bb) {
    int t = blockIdx.x;
    size_t base = (size_t)t * D_;
    float x[3];
    float ss = 0.f;
    #pragma unroll
    for (int c = 0; c < 3; ++c) {
        int i = threadIdx.x + c * 256;
        x[c] = h[base + i];
        ss += x[c] * x[c];
    }
    for (int off = 32; off > 0; off >>= 1) ss += __shfl_down(ss, off);
    __shared__ float red[4];
    int wid = threadIdx.x >> 6, lane = threadIdx.x & 63;
    if (lane == 0) red[wid] = ss;
    __syncthreads();
    float inv = rsqrtf((red[0] + red[1] + red[2] + red[3]) / (float)D_ + 1e-6f);

    float a[6] = {};
    #pragma unroll
    for (int c = 0; c < 3; ++c) {
        int i = threadIdx.x + c * 256;
        float xr = x[c] * inv;
        float xw = xr * rnw[i];
        a[0] += xw * rW[i * 2];
        a[1] += xw * rW[i * 2 + 1];
        float xb = xr * bnw[i];
        #pragma unroll
        for (int j = 0; j < 4; ++j) a[2 + j] += xb * bW[i * 4 + j];
    }
    #pragma unroll
    for (int j = 0; j < 6; ++j)
        for (int off = 32; off > 0; off >>= 1) a[j] += __shfl_down(a[j], off);
    __shared__ float red2[4][6];
    if (lane == 0)
        #pragma unroll
        for (int j = 0; j < 6; ++j) red2[wid][j] = a[j];
    __syncthreads();
    if (threadIdx.x < 6) {
        float s = red2[0][threadIdx.x] + red2[1][threadIdx.x] +
                  red2[2][threadIdx.x] + red2[3][threadIdx.x];
        if (threadIdx.x < 2) out_reward[(size_t)t * 2 + threadIdx.x] = s + rb[threadIdx.x];
        else                 out_box[(size_t)t * 4 + threadIdx.x - 2] = s + bb[threadIdx.x - 2];
    }
}

// ---------------------------------------------------------------------------
extern "C" void kernel_launch(void* const* d_in, const int* in_sizes, int n_in,
                              void* d_out, int out_size, void* d_ws, size_t ws_size,
                              hipStream_t stream) {
    const float* patch        = (const float*)d_in[0];
    const float* box          = (const float*)d_in[1];
    const float* patch_W      = (const float*)d_in[2];
    const float* patch_b      = (const float*)d_in[3];
    const float* box_W        = (const float*)d_in[4];
    const float* box_b        = (const float*)d_in[5];
    const float* Wq           = (const float*)d_in[6];
    const float* Wk           = (const float*)d_in[7];
    const float* Wv           = (const float*)d_in[8];
    const float* Wo           = (const float*)d_in[9];
    const float* attn_norm_w  = (const float*)d_in[10];
    const float* gate_W       = (const float*)d_in[11];
    const float* hidden_W     = (const float*)d_in[12];
    const float* ffn_out_W    = (const float*)d_in[13];
    const float* ffn_norm_w   = (const float*)d_in[14];
    const float* reward_norm_w= (const float*)d_in[15];
    const float* reward_W     = (const float*)d_in[16];
    const float* reward_b     = (const float*)d_in[17];
    const float* label_norm_w = (const float*)d_in[18];
    const float* label_W      = (const float*)d_in[19];
    const float* label_b      = (const float*)d_in[20];
    const float* box_norm_w   = (const float*)d_in[21];
    const float* boxh_W       = (const float*)d_in[22];
    const float* boxh_b       = (const float*)d_in[23];

    char* w = (char*)d_ws;
    auto alloc = [&](size_t bytes) { char* p = w; w += (bytes + 255) & ~(size_t)255; return p; };

    u16*  wqkv_a = (u16*)alloc((size_t)NL_ * 2304 * 768 * 2);
    u16*  wo_a   = (u16*)alloc((size_t)NL_ * 768 * 768 * 2);
    u16*  wgh_a  = (u16*)alloc((size_t)NL_ * 6144 * 768 * 2);
    u16*  wfo_a  = (u16*)alloc((size_t)NL_ * 768 * 3072 * 2);
    u16*  wcat   = (u16*)alloc((size_t)768 * 1536 * 2);
    u16*  wlab   = (u16*)alloc((size_t)1024 * 768 * 2);
    float* bias_c= (float*)alloc((size_t)768 * 4);
    u16*  emb    = (u16*)alloc((size_t)MTOK * 1536 * 2);
    float* h     = (float*)alloc((size_t)MTOK * D_ * 4);
    u16*  hn_bf  = (u16*)alloc((size_t)MTOK * D_ * 2);
    u16*  qkvh   = (u16*)alloc((size_t)MTOK * 2304 * 2);  // [q|k|vT] heads layout
    float* tab   = (float*)alloc((size_t)L_ * 32 * 2 * 4);
    u16*  o_bf   = (u16*)alloc((size_t)MTOK * D_ * 2);
    u16*  ga_bf  = (u16*)alloc((size_t)MTOK * DFF_ * 2);
    float* part  = (float*)alloc((size_t)4 * MTOK * D_ * 4);

    u16* qh = qkvh;
    u16* kh = qkvh + (size_t)MTOK * 768;
    u16* vT = qkvh + (size_t)2 * MTOK * 768;

    dim3 blk(256);

    // one-time converts (all layers, batched)
    k_convT<<<dim3(24, 24), blk, 0, stream>>>(wcat, patch_W, 768, 768, 1536, 1, 0, 0);
    k_convT<<<dim3(24, 24), blk, 0, stream>>>(wcat, box_W,   768, 768, 1536, 1, 0, 768);
    k_convT<<<dim3(32, 24), blk, 0, stream>>>(wlab, label_W, 768, 1000, 768, 1, 0, 0);
    k_addb<<<3, blk, 0, stream>>>(bias_c, patch_b, box_b);
    k_rope_tab<<<(L_ * 32 + 255) / 256, blk, 0, stream>>>(tab);
    k_convT128_qkv<<<dim3(24, 6, 36), blk, 0, stream>>>(wqkv_a, Wq, Wk, Wv);
    k_convT128<<<dim3(24, 6, 12), blk, 0, stream>>>(wo_a, Wo, 768, 768);
    k_convT128_gh<<<dim3(96, 6, 24), blk, 0, stream>>>(wgh_a, gate_W, hidden_W);
    k_convT128<<<dim3(24, 24, 12), blk, 0, stream>>>(wfo_a, ffn_out_W, 3072, 768);
    k_cast<<<(MTOK * 768 / 4 + 255) / 256, blk, 0, stream>>>(emb, patch, MTOK * 768 / 4);
    k_box_sin<<<(MTOK * D_ + 255) / 256, blk, 0, stream>>>(emb, box);

    // embedding: h = [patch|box_sin] @ [patch_W; box_W] + (patch_b+box_b)
    k_gemm_bf16<0><<<dim3(6, 32), blk, 0, stream>>>(h, emb, wcat, bias_c, 1536, 768, 768);
    k_fused_rr<0><<<MTOK, dim3(192), 0, stream>>>(h, nullptr, hn_bf, attn_norm_w);

    for (int ly = 0; ly < NL_; ++ly) {
        const u16* wqkv = wqkv_a + (size_t)ly * 2304 * 768;
        const u16* wo_l = wo_a   + (size_t)ly * 768 * 768;
        const u16* wgh  = wgh_a  + (size_t)ly * 6144 * 768;
        const u16* wfo  = wfo_a  + (size_t)ly * 768 * 3072;
        const float* fnw = ffn_norm_w + (size_t)ly * D_;
        const float* nxt = (ly + 1 < NL_) ? attn_norm_w + (size_t)(ly + 1) * D_
                                          : label_norm_w;

        // QKV GEMM with fused rope (exp2-domain Q) + head relayout + V transpose
        k_gemm_bf16<6><<<dim3(18, 32), blk, 0, stream>>>(qkvh, hn_bf, wqkv, tab, 768, 2304, 2304);
        k_attn3<<<dim3(96, 8), blk, 0, stream>>>(o_bf, qh, kh, vT);
        k_gemm_bf16<4><<<dim3(6, 32, 2), blk, 0, stream>>>(part, o_bf, wo_l, nullptr, 768, 768, 768);
        k_fused_rr<2><<<MTOK, dim3(192), 0, stream>>>(h, part, hn_bf, fnw);

        // GH GEMM: 256x256-tile 512-thread kernel with fused silu
        k_gemm512_gh<<<dim3(24, 16), dim3(512), 0, stream>>>(ga_bf, hn_bf, wgh, 768, 3072);
        k_gemm_bf16<4><<<dim3(6, 32, 4), blk, 0, stream>>>(part, ga_bf, wfo, nullptr, 3072, 768, 768);
        k_fused_rr<4><<<MTOK, dim3(192), 0, stream>>>(h, part, hn_bf, nxt);
    }

    // heads: hn_bf already = rmsnorm(h, label_norm_w)
    float* out_reward = (float*)d_out;
    float* out_label  = out_reward + (size_t)MTOK * 2;
    float* out_box    = out_label + (size_t)MTOK * 1000;

    k_gemm_bf16<0><<<dim3(8, 32), blk, 0, stream>>>(out_label, hn_bf, wlab, label_b, 768, 1000, 1000);
    k_heads3<<<MTOK, blk, 0, stream>>>(out_reward, out_box, h,
                                       reward_norm_w, reward_W, reward_b,
                                       box_norm_w, boxh_W, boxh_b);
}

// Round 15
// 2266.337 us; speedup vs baseline: 1.0834x; 1.0292x over previous
//
#include <hip/hip_runtime.h>
#include <hip/hip_fp16.h>
#include <math.h>
#include <type_traits>

#define B_   8
#define L_   512
#define MTOK 4096           // B_*L_
#define D_   768
#define NH_  12
#define DH_  64
#define DFF_ 3072
#define NL_  12

typedef unsigned short u16;
typedef __attribute__((ext_vector_type(4))) float f32x4;
typedef __attribute__((ext_vector_type(8))) short i16x8;
typedef __attribute__((ext_vector_type(8))) __bf16 b16x8;

// Pick whichever vector type the gfx950 bf16 MFMA builtin accepts.
template <typename A, typename = void>
struct PickFrag { using type = i16x8; };
template <typename A>
struct PickFrag<A, std::void_t<decltype(__builtin_amdgcn_mfma_f32_16x16x32_bf16(
    std::declval<A>(), std::declval<A>(), std::declval<f32x4>(), 0, 0, 0))>> {
  using type = A;
};
using frag_t = typename PickFrag<b16x8>::type;

#if __has_builtin(__builtin_amdgcn_global_load_lds)
#define HAS_GLDS 1
#else
#define HAS_GLDS 0
#endif

#define LOG2E 1.44269504088896340736f

__device__ inline u16 f2bf(float f) {
    unsigned u = __float_as_uint(f);
    unsigned r = u + 0x7fffu + ((u >> 16) & 1u);
    return (u16)(r >> 16);
}
__device__ inline float bf2f(u16 b) { return __uint_as_float(((unsigned)b) << 16); }

// fp16 partial-sum helpers (10-bit mantissa: split-K partial noise ~5e-4)
__device__ inline u16 f2h(float f) {
    __half h = __float2half(f);
    return *reinterpret_cast<u16*>(&h);
}
__device__ inline float h2f(u16 b) {
    __half h = *reinterpret_cast<const __half*>(&b);
    return __half2float(h);
}

// compiler-fenced raw barrier (no vmcnt drain, unlike __syncthreads)
__device__ inline void bar_raw() {
    asm volatile("" ::: "memory");
    __builtin_amdgcn_s_barrier();
    asm volatile("" ::: "memory");
}

// XOR swizzle for 128B-row LDS tiles (u16 index units, 16B granules)
__device__ inline int swz8(int row, int c8) { return c8 ^ ((row & 7) << 3); }

__device__ inline void glds16(const u16* g, u16* l) {
#if HAS_GLDS
    __builtin_amdgcn_global_load_lds(
        (const __attribute__((address_space(1))) void*)g,
        (__attribute__((address_space(3))) void*)l, 16, 0, 0);
#else
    *reinterpret_cast<uint4*>(l) = *reinterpret_cast<const uint4*>(g);
#endif
}

// ---------------------------------------------------------------------------
// box sinusoid embedding -> bf16 into emb[t*1536 + 768 + d]
__global__ void k_box_sin(u16* __restrict__ emb, const float* __restrict__ box) {
    int idx = blockIdx.x * blockDim.x + threadIdx.x;
    if (idx >= MTOK * D_) return;
    int t = idx / D_, d = idx % D_;
    int c = d / 192, r = d % 192, j = r >> 1;
    float theta = __expf(-(float)j * (9.210340371976184f / 96.0f));
    float ang = box[t * 4 + c] * theta;
    emb[(size_t)t * 1536 + 768 + d] = f2bf((r & 1) ? sinf(ang) : cosf(ang));
}

// fp32 patch -> bf16 into emb[t*1536 + c]
__global__ void k_cast(u16* __restrict__ emb, const float* __restrict__ in, int n4) {
    int i = blockIdx.x * blockDim.x + threadIdx.x;
    if (i >= n4) return;            // n4 = MTOK*768/4
    int t = i / 192, c4 = (i % 192) * 4;
    float4 v = *reinterpret_cast<const float4*>(in + (size_t)t * 768 + c4);
    unsigned lo = (unsigned)f2bf(v.x) | ((unsigned)f2bf(v.y) << 16);
    unsigned hi = (unsigned)f2bf(v.z) | ((unsigned)f2bf(v.w) << 16);
    *reinterpret_cast<uint2*>(emb + (size_t)t * 1536 + c4) = make_uint2(lo, hi);
}

// combined bias
__global__ void k_addb(float* __restrict__ dst, const float* __restrict__ a,
                       const float* __restrict__ b) {
    int i = blockIdx.x * blockDim.x + threadIdx.x;
    if (i < D_) dst[i] = a[i] + b[i];
}

// ---------------------------------------------------------------------------
// generic transpose-convert (small one-offs): src (K,N) fp32
// -> dst[(n*rs+ro)*ld + co + k] bf16; zero rows for n>=N.
__global__ __launch_bounds__(256) void k_convT(u16* __restrict__ dst,
                                               const float* __restrict__ src,
                                               int K, int N, int ld, int rs,
                                               int ro, int co) {
    __shared__ float t[32][33];
    int bn = blockIdx.x * 32;
    int bk = blockIdx.y * 32;
    int tx = threadIdx.x % 32, ty = threadIdx.x / 32;
    #pragma unroll
    for (int i = 0; i < 4; ++i) {
        int k = bk + ty + i * 8;
        int n = bn + tx;
        t[ty + i * 8][tx] = (n < N) ? src[(size_t)k * N + n] : 0.0f;
    }
    __syncthreads();
    #pragma unroll
    for (int i = 0; i < 4; ++i) {
        int n = bn + ty + i * 8;
        int k = bk + tx;
        dst[(size_t)(n * rs + ro) * ld + co + k] = f2bf(t[tx][ty + i * 8]);
    }
}

// ---------------------------------------------------------------------------
// batched transposers, 32n x 128k tiles, dense 128B-span stores.
// grid (N/32, K/128, Z).

// plain: src[z] (K,N) -> dst[z] (N,K)
__global__ __launch_bounds__(256) void k_convT128(u16* __restrict__ dst,
                                                  const float* __restrict__ src,
                                                  int K, int N) {
    __shared__ float ts[32][131];
    const float* s = src + (size_t)blockIdx.z * K * N;
    u16* d = dst + (size_t)blockIdx.z * K * N;
    int bn = blockIdx.x * 32, bk = blockIdx.y * 128;
    int t = threadIdx.x, rn = t & 31, kr = t >> 5;
    #pragma unroll
    for (int p = 0; p < 16; ++p) {
        int k = p * 8 + kr;
        ts[rn][k] = s[(size_t)(bk + k) * N + bn + rn];
    }
    __syncthreads();
    int n = t >> 3, c = (t & 7) * 8;
    u16 ta[8], tb[8];
    #pragma unroll
    for (int j = 0; j < 8; ++j) ta[j] = f2bf(ts[n][c + j]);
    #pragma unroll
    for (int j = 0; j < 8; ++j) tb[j] = f2bf(ts[n][64 + c + j]);
    u16* dp = &d[(size_t)(bn + n) * K + bk];
    *reinterpret_cast<uint4*>(dp + c)      = *reinterpret_cast<uint4*>(ta);
    *reinterpret_cast<uint4*>(dp + 64 + c) = *reinterpret_cast<uint4*>(tb);
}

// QKV: z = ly*3 + which; dst slab [3][768][768] per layer
__global__ __launch_bounds__(256) void k_convT128_qkv(u16* __restrict__ dst,
                                                      const float* __restrict__ s0,
                                                      const float* __restrict__ s1,
                                                      const float* __restrict__ s2) {
    __shared__ float ts[32][131];
    int ly = blockIdx.z / 3, which = blockIdx.z % 3;
    const float* s = (which == 0 ? s0 : (which == 1 ? s1 : s2)) + (size_t)ly * 768 * 768;
    u16* d = dst + ((size_t)ly * 3 + which) * 768 * 768;
    int bn = blockIdx.x * 32, bk = blockIdx.y * 128;
    int t = threadIdx.x, rn = t & 31, kr = t >> 5;
    #pragma unroll
    for (int p = 0; p < 16; ++p) {
        int k = p * 8 + kr;
        ts[rn][k] = s[(size_t)(bk + k) * 768 + bn + rn];
    }
    __syncthreads();
    int n = t >> 3, c = (t & 7) * 8;
    u16 ta[8], tb[8];
    #pragma unroll
    for (int j = 0; j < 8; ++j) ta[j] = f2bf(ts[n][c + j]);
    #pragma unroll
    for (int j = 0; j < 8; ++j) tb[j] = f2bf(ts[n][64 + c + j]);
    u16* dp = &d[(size_t)(bn + n) * 768 + bk];
    *reinterpret_cast<uint4*>(dp + c)      = *reinterpret_cast<uint4*>(ta);
    *reinterpret_cast<uint4*>(dp + 64 + c) = *reinterpret_cast<uint4*>(tb);
}

// gate/hidden 16-col interleave: z = ly*2 + which; col n -> row (n>>4)*32+(n&15)+which*16
__global__ __launch_bounds__(256) void k_convT128_gh(u16* __restrict__ dst,
                                                     const float* __restrict__ g,
                                                     const float* __restrict__ h) {
    __shared__ float ts[32][131];
    int ly = blockIdx.z >> 1, which = blockIdx.z & 1;
    const float* s = (which ? h : g) + (size_t)ly * 768 * 3072;
    u16* d = dst + (size_t)ly * 6144 * 768;
    int bn = blockIdx.x * 32, bk = blockIdx.y * 128;
    int t = threadIdx.x, rn = t & 31, kr = t >> 5;
    #pragma unroll
    for (int p = 0; p < 16; ++p) {
        int k = p * 8 + kr;
        ts[rn][k] = s[(size_t)(bk + k) * 3072 + bn + rn];
    }
    __syncthreads();
    int n = t >> 3, c = (t & 7) * 8;
    int ng = bn + n;
    int row = ((ng >> 4) << 5) + (ng & 15) + which * 16;
    u16 ta[8], tb[8];
    #pragma unroll
    for (int j = 0; j < 8; ++j) ta[j] = f2bf(ts[n][c + j]);
    #pragma unroll
    for (int j = 0; j < 8; ++j) tb[j] = f2bf(ts[n][64 + c + j]);
    u16* dp = &d[(size_t)row * 768 + bk];
    *reinterpret_cast<uint4*>(dp + c)      = *reinterpret_cast<uint4*>(ta);
    *reinterpret_cast<uint4*>(dp + 64 + c) = *reinterpret_cast<uint4*>(tb);
}

// ---------------------------------------------------------------------------
// fused (vectorized): h += sum_s part_fp16[s]; hn = bf16(rmsnorm(h, w)).
// one block (192 thr) per token, float4 lanes. S=0: pure rmsnorm (no h write).
template <int S>
__global__ __launch_bounds__(192) void k_fused_rr(float* __restrict__ h,
                                                  const u16* __restrict__ part,
                                                  u16* __restrict__ hn,
                                                  const float* __restrict__ w) {
    int t = blockIdx.x;
    int i4 = threadIdx.x;                       // 0..191 float4 within token
    size_t b4 = (size_t)t * 192 + i4;
    float4 v = reinterpret_cast<const float4*>(h)[b4];
    #pragma unroll
    for (int s = 0; s < S; ++s) {
        uint2 p2 = *reinterpret_cast<const uint2*>(
            part + (size_t)s * MTOK * D_ + b4 * 4);
        const u16* ph = reinterpret_cast<const u16*>(&p2);
        v.x += h2f(ph[0]); v.y += h2f(ph[1]);
        v.z += h2f(ph[2]); v.w += h2f(ph[3]);
    }
    if (S > 0) reinterpret_cast<float4*>(h)[b4] = v;
    float ss = v.x * v.x + v.y * v.y + v.z * v.z + v.w * v.w;
    for (int off = 32; off > 0; off >>= 1) ss += __shfl_down(ss, off);
    __shared__ float red[3];
    int wid = threadIdx.x >> 6, lane = threadIdx.x & 63;
    if (lane == 0) red[wid] = ss;
    __syncthreads();
    float inv = rsqrtf((red[0] + red[1] + red[2]) / (float)D_ + 1e-6f);
    float4 wv = reinterpret_cast<const float4*>(w)[i4];
    unsigned lo = (unsigned)f2bf(v.x * inv * wv.x) | ((unsigned)f2bf(v.y * inv * wv.y) << 16);
    unsigned hi = (unsigned)f2bf(v.z * inv * wv.z) | ((unsigned)f2bf(v.w * inv * wv.w) << 16);
    *reinterpret_cast<uint2*>(hn + (size_t)t * D_ + i4 * 4) = make_uint2(lo, hi);
}

// ---------------------------------------------------------------------------
// one-time RoPE table: tab[(l*32+j)*2] = cos(l*theta_j), +1 = sin
__global__ void k_rope_tab(float* __restrict__ tab) {
    int idx = blockIdx.x * blockDim.x + threadIdx.x;   // 512*32
    if (idx >= L_ * 32) return;
    int l = idx >> 5, j = idx & 31;
    float theta = __expf(-(float)j * (9.210340371976184f / 32.0f));
    float s, c;
    sincosf((float)l * theta, &s, &c);
    tab[idx * 2] = c;
    tab[idx * 2 + 1] = s;
}

// ---------------------------------------------------------------------------
// 256x256-tile bf16 GEMM for the gate/hidden FFN GEMM (silu epilogue).
__global__ __launch_bounds__(512) void k_gemm512_gh(u16* __restrict__ Cp,
                                                    const u16* __restrict__ A,
                                                    const u16* __restrict__ BT,
                                                    int K, int ldC) {
    __shared__ u16 smem[32768];     // As[2][8192] | Bs[2][8192]
    int tid = threadIdx.x;
    int wid = tid >> 6, lane = tid & 63;

    int nx = gridDim.x, ny = gridDim.y;
    int bid = blockIdx.y * nx + blockIdx.x;
    int nwg = nx * ny;
    int cpx = nwg >> 3;
    int swzb = (bid & 7) * cpx + (bid >> 3);
    int by = swzb / nx, bx = swzb % nx;
    int row0 = by * 256, col0 = bx * 256;
    int wr = wid >> 2, wcn = wid & 3;

    int c0 = tid, c1 = tid + 512;
    int r0 = c0 >> 2, r1 = c1 >> 2;
    int gsrc = (((tid & 3) ^ ((tid >> 3) & 3)) << 3);
    const u16* gA0 = A  + (size_t)(row0 + r0) * K + gsrc;
    const u16* gA1 = A  + (size_t)(row0 + r1) * K + gsrc;
    const u16* gB0 = BT + (size_t)(col0 + r0) * K + gsrc;
    const u16* gB1 = BT + (size_t)(col0 + r1) * K + gsrc;

    auto stage = [&](int buf, int kt) {
        u16* Asb = smem + buf * 8192;
        u16* Bsb = smem + 16384 + buf * 8192;
        glds16(gA0 + kt, &Asb[c0 * 8]);
        glds16(gA1 + kt, &Asb[c1 * 8]);
        glds16(gB0 + kt, &Bsb[c0 * 8]);
        glds16(gB1 + kt, &Bsb[c1 * 8]);
    };

    f32x4 acc[8][4] = {};
    int lr = lane & 15, lg = lane >> 4;
    int lk = (((lg ^ ((lr >> 1) & 3))) << 3);

    stage(0, 0);
    int cur = 0;
    for (int kt = 0; kt < K; kt += 32) {
        bool has_next = (kt + 32 < K);
        if (has_next) stage(cur ^ 1, kt + 32);
        if (has_next) asm volatile("s_waitcnt vmcnt(4) lgkmcnt(0)" ::: "memory");
        else          asm volatile("s_waitcnt vmcnt(0) lgkmcnt(0)" ::: "memory");
        __builtin_amdgcn_sched_barrier(0);
        bar_raw();
        const u16* Asb = smem + cur * 8192;
        const u16* Bsb = smem + 16384 + cur * 8192;
        frag_t af[8], bfr[4];
        #pragma unroll
        for (int m = 0; m < 8; ++m)
            af[m] = *reinterpret_cast<const frag_t*>(&Asb[(wr * 128 + m * 16 + lr) * 32 + lk]);
        #pragma unroll
        for (int n = 0; n < 4; ++n)
            bfr[n] = *reinterpret_cast<const frag_t*>(&Bsb[(wcn * 64 + n * 16 + lr) * 32 + lk]);
        #pragma unroll
        for (int m = 0; m < 8; ++m)
            #pragma unroll
            for (int n = 0; n < 4; ++n)
                acc[m][n] = __builtin_amdgcn_mfma_f32_16x16x32_bf16(af[m], bfr[n], acc[m][n], 0, 0, 0);
        bar_raw();
        cur ^= 1;
    }

    int lcol = lane & 15, rb = (lane >> 4) * 4;
    #pragma unroll
    for (int m = 0; m < 8; ++m) {
        #pragma unroll
        for (int np = 0; np < 2; ++np) {
            int ocol = (col0 >> 1) + wcn * 32 + np * 16 + lcol;
            #pragma unroll
            for (int e = 0; e < 4; ++e) {
                int row = row0 + wr * 128 + m * 16 + rb + e;
                float g = acc[m][2 * np][e], hv = acc[m][2 * np + 1][e];
                float s = g / (1.0f + __expf(-g));
                Cp[(size_t)row * ldC + ocol] = f2bf(s * hv);
            }
        }
    }
}

// ---------------------------------------------------------------------------
// bf16 MFMA GEMM (128x128), double-buffered, counted-vmcnt, XCD swizzle, split-K.
// MODE 0: C=acc(+bias) f32   MODE 3: C=acc bf16
// MODE 6: fused QKV epilogue (rope Q/K [exp2-domain Q scale] + V transpose)
// MODE 7: fp16 partial store to (u16*)Cp + sk*M*ldC (split-K, half traffic)
template <int MODE>
__global__ __launch_bounds__(256) void k_gemm_bf16(void* __restrict__ Cp,
                                                   const u16* __restrict__ A,
                                                   const u16* __restrict__ BT,
                                                   const float* __restrict__ bias,
                                                   int K, int Nout, int ldC) {
    __shared__ u16 smem[16384];          // As[2][4096] | Bs[2][4096]
    int tid = threadIdx.x;
    int wid = tid >> 6, lane = tid & 63;

    int nx = gridDim.x, ny = gridDim.y, nz = gridDim.z;
    int bid = ((blockIdx.z * ny) + blockIdx.y) * nx + blockIdx.x;
    int nwg = nx * ny * nz;
    int cpx = nwg >> 3;
    int swz = (bid & 7) * cpx + (bid >> 3);
    int sk  = swz / (nx * ny);
    int rem = swz % (nx * ny);
    int by = rem / nx, bx = rem % nx;
    int row0 = by * 128, col0 = bx * 128;
    int wr = wid >> 1, wc = wid & 1;

    int Klen = K / nz;
    int kbeg = sk * Klen;

    int c0 = wid * 128 + lane;          // 0..511
    int c1 = c0 + 64;
    int r0 = c0 >> 2, kc0 = (c0 & 3) * 8;
    int r1 = c1 >> 2, kc1 = (c1 & 3) * 8;
    const u16* gA0 = A  + (size_t)(row0 + r0) * K + kbeg + kc0;
    const u16* gA1 = A  + (size_t)(row0 + r1) * K + kbeg + kc1;
    const u16* gB0 = BT + (size_t)(col0 + r0) * K + kbeg + kc0;
    const u16* gB1 = BT + (size_t)(col0 + r1) * K + kbeg + kc1;

    auto stage = [&](int buf, int kt) {
        u16* Asb = smem + buf * 4096;
        u16* Bsb = smem + 8192 + buf * 4096;
        glds16(gA0 + kt, &Asb[c0 * 8]);
        glds16(gA1 + kt, &Asb[c1 * 8]);
        glds16(gB0 + kt, &Bsb[c0 * 8]);
        glds16(gB1 + kt, &Bsb[c1 * 8]);
    };

    f32x4 acc[4][4] = {};
    int lrow = lane & 15, lk = (lane >> 4) * 8;

    stage(0, 0);
    int cur = 0;
    for (int kt = 0; kt < Klen; kt += 32) {
        bool has_next = (kt + 32 < Klen);
        if (has_next) stage(cur ^ 1, kt + 32);
        if (has_next) asm volatile("s_waitcnt vmcnt(4) lgkmcnt(0)" ::: "memory");
        else          asm volatile("s_waitcnt vmcnt(0) lgkmcnt(0)" ::: "memory");
        __builtin_amdgcn_sched_barrier(0);
        bar_raw();
        const u16* Asb = smem + cur * 4096;
        const u16* Bsb = smem + 8192 + cur * 4096;
        frag_t af[4], bfr[4];
        #pragma unroll
        for (int m = 0; m < 4; ++m)
            af[m] = *reinterpret_cast<const frag_t*>(&Asb[(wr * 64 + m * 16 + lrow) * 32 + lk]);
        #pragma unroll
        for (int n = 0; n < 4; ++n)
            bfr[n] = *reinterpret_cast<const frag_t*>(&Bsb[(wc * 64 + n * 16 + lrow) * 32 + lk]);
        #pragma unroll
        for (int m = 0; m < 4; ++m)
            #pragma unroll
            for (int n = 0; n < 4; ++n)
                acc[m][n] = __builtin_amdgcn_mfma_f32_16x16x32_bf16(af[m], bfr[n], acc[m][n], 0, 0, 0);
        bar_raw();
        cur ^= 1;
    }

    int lcol = lane & 15, rb = (lane >> 4) * 4;

    if (MODE == 6) {
        u16* qkvh = (u16*)Cp;
        const float* tab = bias;
        if (col0 >= 1536) {
            int head_base = (col0 - 1536) >> 6;
            int bb = row0 >> 9;
            int l0 = row0 & 511;
            #pragma unroll
            for (int pass = 0; pass < 2; ++pass) {
                if (wc == pass) {
                    #pragma unroll
                    for (int m = 0; m < 4; ++m) {
                        #pragma unroll
                        for (int n = 0; n < 4; ++n) {
                            int dl = n * 16 + lcol;
                            int rl = wr * 64 + m * 16 + rb;
                            u16 tmp[4];
                            #pragma unroll
                            for (int e = 0; e < 4; ++e) tmp[e] = f2bf(acc[m][n][e]);
                            *reinterpret_cast<uint2*>(&smem[dl * 136 + rl]) =
                                *reinterpret_cast<uint2*>(tmp);
                        }
                    }
                }
                __syncthreads();
                int head = head_base + pass;
                size_t vbase = (size_t)2 * MTOK * 768 +
                               ((size_t)(bb * NH_ + head) * 64) * 512;
                #pragma unroll
                for (int it = 0; it < 4; ++it) {
                    int dd = it * 16 + (tid >> 4);
                    int rr = (tid & 15) * 8;
                    uint4 v4 = *reinterpret_cast<const uint4*>(&smem[dd * 136 + rr]);
                    *reinterpret_cast<uint4*>(&qkvh[vbase + (size_t)dd * 512 + l0 + rr]) = v4;
                }
                __syncthreads();
            }
        } else {
            int sec = col0 / 768;               // 0=Q, 1=K (uniform per block)
            // exp2-domain: fold log2(e) into Q so attn uses bare v_exp_f32
            float qscale = (sec == 0) ? 0.125f * LOG2E : 1.0f;
            #pragma unroll
            for (int m = 0; m < 4; ++m) {
                #pragma unroll
                for (int n = 0; n < 4; ++n) {
                    int col = col0 + wc * 64 + n * 16 + lcol;
                    int head = (col % 768) >> 6;
                    int d = col & 63;
                    #pragma unroll
                    for (int e = 0; e < 4; ++e) {
                        int row = row0 + wr * 64 + m * 16 + rb + e;
                        int bb = row >> 9, l = row & 511;
                        float v = acc[m][n][e];
                        float p = __shfl_xor(v, 1);
                        float2 cs = *reinterpret_cast<const float2*>(
                            tab + ((size_t)l * 32 + (d >> 1)) * 2);
                        float r = (d & 1) ? (p * cs.y + v * cs.x)
                                          : (v * cs.x - p * cs.y);
                        r *= qscale;
                        qkvh[(size_t)sec * MTOK * 768 +
                             ((size_t)(bb * NH_ + head) * 512 + l) * 64 + d] = f2bf(r);
                    }
                }
            }
        }
        return;
    }

    u16* Cph = (MODE == 7)
        ? ((u16*)Cp + (size_t)sk * (size_t)(ny * 128) * ldC) : (u16*)Cp;
    #pragma unroll
    for (int m = 0; m < 4; ++m) {
        #pragma unroll
        for (int n = 0; n < 4; ++n) {
            int col = col0 + wc * 64 + n * 16 + lcol;
            if (col >= Nout) continue;
            #pragma unroll
            for (int e = 0; e < 4; ++e) {
                int row = row0 + wr * 64 + m * 16 + rb + e;
                float v = acc[m][n][e];
                size_t off = (size_t)row * ldC + col;
                if (MODE == 0) {
                    if (bias) v += bias[col];
                    ((float*)Cp)[off] = v;
                } else if (MODE == 3) {
                    ((u16*)Cp)[off] = f2bf(v);
                } else if (MODE == 7) {
                    Cph[off] = f2h(v);
                }
            }
        }
    }
}

// ---------------------------------------------------------------------------
// MFMA flash attention (exp2-domain scores; Q pre-scaled by 0.125*log2e).
// grid (96 bh, 8 qb), 256 thr = 4 waves x 16 q-rows.
__global__ __launch_bounds__(256) void k_attn3(u16* __restrict__ o,
                                               const u16* __restrict__ qh,
                                               const u16* __restrict__ kh,
                                               const u16* __restrict__ vT) {
    int bh = blockIdx.x, qb = blockIdx.y;
    int b = bh / NH_, hh = bh % NH_;
    int tid = threadIdx.x, wid = tid >> 6, lane = tid & 63;
    __shared__ u16 Qs[64][72], Ps[64][72];
    __shared__ u16 Ks[64 * 64], Vs[64 * 64];

    #pragma unroll
    for (int i = 0; i < 2; ++i) {
        int idx = tid + i * 256;
        int r = idx >> 3, c8 = (idx & 7) * 8;
        uint4 v4 = *reinterpret_cast<const uint4*>(
            qh + ((size_t)bh * L_ + qb * 64 + r) * 64 + c8);
        *reinterpret_cast<uint4*>(&Qs[r][c8]) = v4;
    }
    __syncthreads();

    int lr = lane & 15, lg = lane >> 4;
    frag_t aq[2];
    #pragma unroll
    for (int kd = 0; kd < 2; ++kd)
        aq[kd] = *reinterpret_cast<const frag_t*>(&Qs[wid * 16 + lr][kd * 32 + lg * 8]);

    int sr0 = tid >> 3, sc8 = (tid & 7) * 8;
    int sr1 = sr0 + 32;

    f32x4 accO[4] = {};
    float M[4], S[4];
    #pragma unroll
    for (int e = 0; e < 4; ++e) { M[e] = -INFINITY; S[e] = 0.f; }

    uint4 kreg0 = *reinterpret_cast<const uint4*>(kh + ((size_t)bh * L_ + sr0) * 64 + sc8);
    uint4 kreg1 = *reinterpret_cast<const uint4*>(kh + ((size_t)bh * L_ + sr1) * 64 + sc8);
    uint4 vreg0 = *reinterpret_cast<const uint4*>(vT + ((size_t)bh * 64 + sr0) * L_ + sc8);
    uint4 vreg1 = *reinterpret_cast<const uint4*>(vT + ((size_t)bh * 64 + sr1) * L_ + sc8);

    for (int kb = 0; kb <= qb; ++kb) {
        __syncthreads();
        *reinterpret_cast<uint4*>(&Ks[sr0 * 64 + swz8(sr0, sc8)]) = kreg0;
        *reinterpret_cast<uint4*>(&Ks[sr1 * 64 + swz8(sr1, sc8)]) = kreg1;
        *reinterpret_cast<uint4*>(&Vs[sr0 * 64 + swz8(sr0, sc8)]) = vreg0;
        *reinterpret_cast<uint4*>(&Vs[sr1 * 64 + swz8(sr1, sc8)]) = vreg1;
        __syncthreads();
        if (kb < qb) {
            int nb = (kb + 1) * 64;
            kreg0 = *reinterpret_cast<const uint4*>(kh + ((size_t)bh * L_ + nb + sr0) * 64 + sc8);
            kreg1 = *reinterpret_cast<const uint4*>(kh + ((size_t)bh * L_ + nb + sr1) * 64 + sc8);
            vreg0 = *reinterpret_cast<const uint4*>(vT + ((size_t)bh * 64 + sr0) * L_ + nb + sc8);
            vreg1 = *reinterpret_cast<const uint4*>(vT + ((size_t)bh * 64 + sr1) * L_ + nb + sc8);
        }

        f32x4 sv[4];
        __builtin_amdgcn_s_setprio(1);
        #pragma unroll
        for (int ct = 0; ct < 4; ++ct) {
            int krow = ct * 16 + lr;
            frag_t bk0 = *reinterpret_cast<const frag_t*>(&Ks[krow * 64 + swz8(krow, lg * 8)]);
            frag_t bk1 = *reinterpret_cast<const frag_t*>(&Ks[krow * 64 + swz8(krow, 32 + lg * 8)]);
            f32x4 z = {0.f, 0.f, 0.f, 0.f};
            z = __builtin_amdgcn_mfma_f32_16x16x32_bf16(aq[0], bk0, z, 0, 0, 0);
            sv[ct] = __builtin_amdgcn_mfma_f32_16x16x32_bf16(aq[1], bk1, z, 0, 0, 0);
        }
        __builtin_amdgcn_s_setprio(0);

        bool diag = (kb == qb);
        float mxv[4];
        #pragma unroll
        for (int e = 0; e < 4; ++e) {
            int qg = qb * 64 + wid * 16 + lg * 4 + e;
            float mx = -1e30f;
            #pragma unroll
            for (int ct = 0; ct < 4; ++ct) {
                float s = sv[ct][e];
                if (diag && (kb * 64 + ct * 16 + lr > qg)) s = -1e30f;
                sv[ct][e] = s;
                mx = fmaxf(mx, s);
            }
            #pragma unroll
            for (int msk = 8; msk; msk >>= 1) mx = fmaxf(mx, __shfl_xor(mx, msk));
            mxv[e] = mx;
        }
        bool grow = (mxv[0] > M[0]) | (mxv[1] > M[1]) |
                    (mxv[2] > M[2]) | (mxv[3] > M[3]);
        if (__any(grow)) {
            #pragma unroll
            for (int e = 0; e < 4; ++e) {
                float newM = fmaxf(M[e], mxv[e]);
                float ps = 0.f;
                #pragma unroll
                for (int ct = 0; ct < 4; ++ct) {
                    float p = exp2f(sv[ct][e] - newM);
                    sv[ct][e] = p;
                    ps += p;
                }
                #pragma unroll
                for (int msk = 8; msk; msk >>= 1) ps += __shfl_xor(ps, msk);
                float esc = exp2f(M[e] - newM);
                S[e] = S[e] * esc + ps;
                M[e] = newM;
                #pragma unroll
                for (int dt = 0; dt < 4; ++dt) accO[dt][e] *= esc;
            }
        } else {
            #pragma unroll
            for (int e = 0; e < 4; ++e) {
                float ps = 0.f;
                #pragma unroll
                for (int ct = 0; ct < 4; ++ct) {
                    float p = exp2f(sv[ct][e] - M[e]);
                    sv[ct][e] = p;
                    ps += p;
                }
                #pragma unroll
                for (int msk = 8; msk; msk >>= 1) ps += __shfl_xor(ps, msk);
                S[e] += ps;
            }
        }

        #pragma unroll
        for (int ct = 0; ct < 4; ++ct)
            #pragma unroll
            for (int e = 0; e < 4; ++e)
                Ps[wid * 16 + lg * 4 + e][ct * 16 + lr] = f2bf(sv[ct][e]);

        frag_t pa0 = *reinterpret_cast<const frag_t*>(&Ps[wid * 16 + lr][lg * 8]);
        frag_t pa1 = *reinterpret_cast<const frag_t*>(&Ps[wid * 16 + lr][32 + lg * 8]);
        __builtin_amdgcn_s_setprio(1);
        #pragma unroll
        for (int dt = 0; dt < 4; ++dt) {
            int vrow = dt * 16 + lr;
            frag_t bv0 = *reinterpret_cast<const frag_t*>(&Vs[vrow * 64 + swz8(vrow, lg * 8)]);
            frag_t bv1 = *reinterpret_cast<const frag_t*>(&Vs[vrow * 64 + swz8(vrow, 32 + lg * 8)]);
            accO[dt] = __builtin_amdgcn_mfma_f32_16x16x32_bf16(pa0, bv0, accO[dt], 0, 0, 0);
            accO[dt] = __builtin_amdgcn_mfma_f32_16x16x32_bf16(pa1, bv1, accO[dt], 0, 0, 0);
        }
        __builtin_amdgcn_s_setprio(0);
    }

    #pragma unroll
    for (int dt = 0; dt < 4; ++dt) {
        #pragma unroll
        for (int e = 0; e < 4; ++e) {
            int row = b * L_ + qb * 64 + wid * 16 + lg * 4 + e;
            o[(size_t)row * D_ + hh * 64 + dt * 16 + lr] = f2bf(accO[dt][e] / S[e]);
        }
    }
}

// ---------------------------------------------------------------------------
// tiny heads: per token, shared rsqrt; reward (2) + box (4) dot products.
__global__ __launch_bounds__(256) void k_heads3(float* __restrict__ out_reward,
                                                float* __restrict__ out_box,
                                                const float* __restrict__ h,
                                                const float* __restrict__ rnw,
                                                const float* __restrict__ rW,
                                                const float* __restrict__ rb,
                                                const float* __restrict__ bnw,
                                                const float* __restrict__ bW,
                                                const float* __restrict__ bb) {
    int t = blockIdx.x;
    size_t base = (size_t)t * D_;
    float x[3];
    float ss = 0.f;
    #pragma unroll
    for (int c = 0; c < 3; ++c) {
        int i = threadIdx.x + c * 256;
        x[c] = h[base + i];
        ss += x[c] * x[c];
    }
    for (int off = 32; off > 0; off >>= 1) ss += __shfl_down(ss, off);
    __shared__ float red[4];
    int wid = threadIdx.x >> 6, lane = threadIdx.x & 63;
    if (lane == 0) red[wid] = ss;
    __syncthreads();
    float inv = rsqrtf((red[0] + red[1] + red[2] + red[3]) / (float)D_ + 1e-6f);

    float a[6] = {};
    #pragma unroll
    for (int c = 0; c < 3; ++c) {
        int i = threadIdx.x + c * 256;
        float xr = x[c] * inv;
        float xw = xr * rnw[i];
        a[0] += xw * rW[i * 2];
        a[1] += xw * rW[i * 2 + 1];
        float xb = xr * bnw[i];
        #pragma unroll
        for (int j = 0; j < 4; ++j) a[2 + j] += xb * bW[i * 4 + j];
    }
    #pragma unroll
    for (int j = 0; j < 6; ++j)
        for (int off = 32; off > 0; off >>= 1) a[j] += __shfl_down(a[j], off);
    __shared__ float red2[4][6];
    if (lane == 0)
        #pragma unroll
        for (int j = 0; j < 6; ++j) red2[wid][j] = a[j];
    __syncthreads();
    if (threadIdx.x < 6) {
        float s = red2[0][threadIdx.x] + red2[1][threadIdx.x] +
                  red2[2][threadIdx.x] + red2[3][threadIdx.x];
        if (threadIdx.x < 2) out_reward[(size_t)t * 2 + threadIdx.x] = s + rb[threadIdx.x];
        else                 out_box[(size_t)t * 4 + threadIdx.x - 2] = s + bb[threadIdx.x - 2];
    }
}

// ---------------------------------------------------------------------------
extern "C" void kernel_launch(void* const* d_in, const int* in_sizes, int n_in,
                              void* d_out, int out_size, void* d_ws, size_t ws_size,
                              hipStream_t stream) {
    const float* patch        = (const float*)d_in[0];
    const float* box          = (const float*)d_in[1];
    const float* patch_W      = (const float*)d_in[2];
    const float* patch_b      = (const float*)d_in[3];
    const float* box_W        = (const float*)d_in[4];
    const float* box_b        = (const float*)d_in[5];
    const float* Wq           = (const float*)d_in[6];
    const float* Wk           = (const float*)d_in[7];
    const float* Wv           = (const float*)d_in[8];
    const float* Wo           = (const float*)d_in[9];
    const float* attn_norm_w  = (const float*)d_in[10];
    const float* gate_W       = (const float*)d_in[11];
    const float* hidden_W     = (const float*)d_in[12];
    const float* ffn_out_W    = (const float*)d_in[13];
    const float* ffn_norm_w   = (const float*)d_in[14];
    const float* reward_norm_w= (const float*)d_in[15];
    const float* reward_W     = (const float*)d_in[16];
    const float* reward_b     = (const float*)d_in[17];
    const float* label_norm_w = (const float*)d_in[18];
    const float* label_W      = (const float*)d_in[19];
    const float* label_b      = (const float*)d_in[20];
    const float* box_norm_w   = (const float*)d_in[21];
    const float* boxh_W       = (const float*)d_in[22];
    const float* boxh_b       = (const float*)d_in[23];

    char* w = (char*)d_ws;
    auto alloc = [&](size_t bytes) { char* p = w; w += (bytes + 255) & ~(size_t)255; return p; };

    u16*  wqkv_a = (u16*)alloc((size_t)NL_ * 2304 * 768 * 2);
    u16*  wo_a   = (u16*)alloc((size_t)NL_ * 768 * 768 * 2);
    u16*  wgh_a  = (u16*)alloc((size_t)NL_ * 6144 * 768 * 2);
    u16*  wfo_a  = (u16*)alloc((size_t)NL_ * 768 * 3072 * 2);
    u16*  wcat   = (u16*)alloc((size_t)768 * 1536 * 2);
    u16*  wlab   = (u16*)alloc((size_t)1024 * 768 * 2);
    float* bias_c= (float*)alloc((size_t)768 * 4);
    u16*  emb    = (u16*)alloc((size_t)MTOK * 1536 * 2);
    float* h     = (float*)alloc((size_t)MTOK * D_ * 4);
    u16*  hn_bf  = (u16*)alloc((size_t)MTOK * D_ * 2);
    u16*  qkvh   = (u16*)alloc((size_t)MTOK * 2304 * 2);  // [q|k|vT] heads layout
    float* tab   = (float*)alloc((size_t)L_ * 32 * 2 * 4);
    u16*  o_bf   = (u16*)alloc((size_t)MTOK * D_ * 2);
    u16*  ga_bf  = (u16*)alloc((size_t)MTOK * DFF_ * 2);
    u16*  part   = (u16*)alloc((size_t)4 * MTOK * D_ * 2);  // fp16 split-K partials

    u16* qh = qkvh;
    u16* kh = qkvh + (size_t)MTOK * 768;
    u16* vT = qkvh + (size_t)2 * MTOK * 768;

    dim3 blk(256);

    // one-time converts (all layers, batched)
    k_convT<<<dim3(24, 24), blk, 0, stream>>>(wcat, patch_W, 768, 768, 1536, 1, 0, 0);
    k_convT<<<dim3(24, 24), blk, 0, stream>>>(wcat, box_W,   768, 768, 1536, 1, 0, 768);
    k_convT<<<dim3(32, 24), blk, 0, stream>>>(wlab, label_W, 768, 1000, 768, 1, 0, 0);
    k_addb<<<3, blk, 0, stream>>>(bias_c, patch_b, box_b);
    k_rope_tab<<<(L_ * 32 + 255) / 256, blk, 0, stream>>>(tab);
    k_convT128_qkv<<<dim3(24, 6, 36), blk, 0, stream>>>(wqkv_a, Wq, Wk, Wv);
    k_convT128<<<dim3(24, 6, 12), blk, 0, stream>>>(wo_a, Wo, 768, 768);
    k_convT128_gh<<<dim3(96, 6, 24), blk, 0, stream>>>(wgh_a, gate_W, hidden_W);
    k_convT128<<<dim3(24, 24, 12), blk, 0, stream>>>(wfo_a, ffn_out_W, 3072, 768);
    k_cast<<<(MTOK * 768 / 4 + 255) / 256, blk, 0, stream>>>(emb, patch, MTOK * 768 / 4);
    k_box_sin<<<(MTOK * D_ + 255) / 256, blk, 0, stream>>>(emb, box);

    // embedding: h = [patch|box_sin] @ [patch_W; box_W] + (patch_b+box_b)
    k_gemm_bf16<0><<<dim3(6, 32), blk, 0, stream>>>(h, emb, wcat, bias_c, 1536, 768, 768);
    k_fused_rr<0><<<MTOK, dim3(192), 0, stream>>>(h, nullptr, hn_bf, attn_norm_w);

    for (int ly = 0; ly < NL_; ++ly) {
        const u16* wqkv = wqkv_a + (size_t)ly * 2304 * 768;
        const u16* wo_l = wo_a   + (size_t)ly * 768 * 768;
        const u16* wgh  = wgh_a  + (size_t)ly * 6144 * 768;
        const u16* wfo  = wfo_a  + (size_t)ly * 768 * 3072;
        const float* fnw = ffn_norm_w + (size_t)ly * D_;
        const float* nxt = (ly + 1 < NL_) ? attn_norm_w + (size_t)(ly + 1) * D_
                                          : label_norm_w;

        // QKV GEMM with fused rope (exp2-domain Q) + head relayout + V transpose
        k_gemm_bf16<6><<<dim3(18, 32), blk, 0, stream>>>(qkvh, hn_bf, wqkv, tab, 768, 2304, 2304);
        k_attn3<<<dim3(96, 8), blk, 0, stream>>>(o_bf, qh, kh, vT);
        k_gemm_bf16<7><<<dim3(6, 32, 2), blk, 0, stream>>>(part, o_bf, wo_l, nullptr, 768, 768, 768);
        k_fused_rr<2><<<MTOK, dim3(192), 0, stream>>>(h, part, hn_bf, fnw);

        // GH GEMM: 256x256-tile 512-thread kernel with fused silu
        k_gemm512_gh<<<dim3(24, 16), dim3(512), 0, stream>>>(ga_bf, hn_bf, wgh, 768, 3072);
        k_gemm_bf16<7><<<dim3(6, 32, 4), blk, 0, stream>>>(part, ga_bf, wfo, nullptr, 3072, 768, 768);
        k_fused_rr<4><<<MTOK, dim3(192), 0, stream>>>(h, part, hn_bf, nxt);
    }

    // heads: hn_bf already = rmsnorm(h, label_norm_w)
    float* out_reward = (float*)d_out;
    float* out_label  = out_reward + (size_t)MTOK * 2;
    float* out_box    = out_label + (size_t)MTOK * 1000;

    k_gemm_bf16<0><<<dim3(8, 32), blk, 0, stream>>>(out_label, hn_bf, wlab, label_b, 768, 1000, 1000);
    k_heads3<<<MTOK, blk, 0, stream>>>(out_reward, out_box, h,
                                       reward_norm_w, reward_W, reward_b,
                                       box_norm_w, boxh_W, boxh_b);
}